// Round 1
// baseline (22003.734 us; speedup 1.0000x reference)
//
#include <hip/hip_runtime.h>
#include <hip/hip_bf16.h>

#define B_ 32
#define C_ 768
#define NH_ 12
#define HD_ 64
#define NP_ 196
#define NTOK 197
#define NKEEP 98
#define NCLS_ 1000

// ---------------- block reduction (256 threads) ----------------
__device__ __forceinline__ float blockReduceSum256(float v) {
    __shared__ float red[4];
    const int lane = threadIdx.x & 63, w = threadIdx.x >> 6;
#pragma unroll
    for (int off = 32; off; off >>= 1) v += __shfl_down(v, off);
    __syncthreads();              // protect red[] reuse across calls
    if (lane == 0) red[w] = v;
    __syncthreads();
    return red[0] + red[1] + red[2] + red[3];
}

// ---------------- patchify: (B,3,224,224) -> (B*196, 768) ----------------
__global__ __launch_bounds__(256) void patchify_kernel(const float* __restrict__ img,
                                                       float* __restrict__ patches)
{
    const int bp = blockIdx.x;               // b*196 + p
    const int b = bp / NP_, p = bp % NP_;
    const int gy = p / 14, gx = p % 14;
    const int tid = threadIdx.x;
#pragma unroll
    for (int j = 0; j < 3; ++j) {
        const int e = tid + j * 256;         // c*256 + py*16 + px
        const int c = e >> 8, rem = e & 255, py = rem >> 4, px = rem & 15;
        patches[(size_t)bp * C_ + e] =
            img[(((size_t)b * 3 + c) * 224 + gy * 16 + py) * 224 + gx * 16 + px];
    }
}

// ---------------- x = concat(cls, pemb) + pos ----------------
__global__ __launch_bounds__(256) void assemble_x_kernel(const float* __restrict__ pemb,
                                                         const float* __restrict__ cls_tok,
                                                         const float* __restrict__ pos,
                                                         float* __restrict__ x)
{
    const int b = blockIdx.x, t = blockIdx.y, tid = threadIdx.x;
#pragma unroll
    for (int j = 0; j < 3; ++j) {
        const int c = tid + j * 256;
        const float v = (t == 0) ? cls_tok[c] : pemb[((size_t)b * NP_ + (t - 1)) * C_ + c];
        x[((size_t)b * NTOK + t) * C_ + c] = v + pos[(size_t)t * C_ + c];
    }
}

// ---------------- layernorm over C=768 (one block per row) ----------------
__global__ __launch_bounds__(256) void ln_kernel(const float* __restrict__ x,
                                                 const float* __restrict__ g,
                                                 const float* __restrict__ b,
                                                 float* __restrict__ out,
                                                 long long inRowStride)
{
    const int tok = blockIdx.x, tid = threadIdx.x;
    const float* xr = x + (size_t)tok * inRowStride;
    const float v0 = xr[tid], v1 = xr[tid + 256], v2 = xr[tid + 512];
    const float mu = blockReduceSum256(v0 + v1 + v2) * (1.f / C_);
    const float d0 = v0 - mu, d1 = v1 - mu, d2 = v2 - mu;
    const float var = blockReduceSum256(d0 * d0 + d1 * d1 + d2 * d2) * (1.f / C_);
    const float rs = rsqrtf(var + 1e-6f);
    float* orow = out + (size_t)tok * C_;
    orow[tid]       = d0 * rs * g[tid]       + b[tid];
    orow[tid + 256] = d1 * rs * g[tid + 256] + b[tid + 256];
    orow[tid + 512] = d2 * rs * g[tid + 512] + b[tid + 512];
}

// ---------------- generic fp32 GEMM: C = act(A@W + bias) (+res) ----------------
// 128x128 tile, BK=16, 256 threads, 8x8 microtile with 16-strided rows/cols
// (strided layout -> As reads broadcast, Ws reads conflict-free)
__global__ __launch_bounds__(256) void gemm_kernel(const float* __restrict__ A,
                                                   const float* __restrict__ W,
                                                   const float* __restrict__ bias,
                                                   const float* res, float* Cout,
                                                   int M, int N, int K, int act)
{
    __shared__ float As[16][132];   // [k][m], padded
    __shared__ float Ws[16][128];   // [k][n]
    const int tid = threadIdx.x;
    const int bm = blockIdx.y << 7;
    const int bn = blockIdx.x << 7;
    const int tx = tid & 15, ty = tid >> 4;
    const int arow = tid >> 1, acol = (tid & 1) << 3;
    const int wrow = tid >> 4, wcol = (tid & 15) << 3;
    float acc[8][8] = {};
    for (int k0 = 0; k0 < K; k0 += 16) {
        float4 a0 = make_float4(0.f, 0.f, 0.f, 0.f), a1 = a0;
        if (bm + arow < M) {
            const float* ap = A + (size_t)(bm + arow) * K + k0 + acol;
            a0 = *(const float4*)ap;
            a1 = *(const float4*)(ap + 4);
        }
        As[acol + 0][arow] = a0.x; As[acol + 1][arow] = a0.y;
        As[acol + 2][arow] = a0.z; As[acol + 3][arow] = a0.w;
        As[acol + 4][arow] = a1.x; As[acol + 5][arow] = a1.y;
        As[acol + 6][arow] = a1.z; As[acol + 7][arow] = a1.w;
        {
            const int gc = bn + wcol;
            const float* wp = W + (size_t)(k0 + wrow) * N + gc;
            float4 w0, w1;
            if (gc + 7 < N) { w0 = *(const float4*)wp; w1 = *(const float4*)(wp + 4); }
            else {
                float tmp[8];
#pragma unroll
                for (int j = 0; j < 8; ++j) tmp[j] = (gc + j < N) ? wp[j] : 0.f;
                w0 = make_float4(tmp[0], tmp[1], tmp[2], tmp[3]);
                w1 = make_float4(tmp[4], tmp[5], tmp[6], tmp[7]);
            }
            *(float4*)&Ws[wrow][wcol]     = w0;
            *(float4*)&Ws[wrow][wcol + 4] = w1;
        }
        __syncthreads();
#pragma unroll
        for (int k = 0; k < 16; ++k) {
            float a[8], bb[8];
#pragma unroll
            for (int i = 0; i < 8; ++i) a[i] = As[k][ty + (i << 4)];
#pragma unroll
            for (int j = 0; j < 8; ++j) bb[j] = Ws[k][tx + (j << 4)];
#pragma unroll
            for (int i = 0; i < 8; ++i)
#pragma unroll
                for (int j = 0; j < 8; ++j)
                    acc[i][j] = fmaf(a[i], bb[j], acc[i][j]);
        }
        __syncthreads();
    }
#pragma unroll
    for (int i = 0; i < 8; ++i) {
        const int gr = bm + ty + (i << 4);
        if (gr >= M) continue;
#pragma unroll
        for (int j = 0; j < 8; ++j) {
            const int gc = bn + tx + (j << 4);
            if (gc >= N) continue;
            float v = acc[i][j];
            if (bias) v += bias[gc];
            if (act == 1) v = 0.5f * v * (1.f + erff(v * 0.70710678118654752f));
            if (res) v += res[(size_t)gr * N + gc];
            Cout[(size_t)gr * N + gc] = v;
        }
    }
}

// ---------------- attention: one block per (b,h), 4 waves, wave-per-query ----------------
// K staged in LDS with 16B-chunk XOR swizzle (row stride 256B would be fully bank-conflicted)
__global__ __launch_bounds__(256) void attn_kernel(const float* __restrict__ qk,
                                                   const float* __restrict__ vbuf,
                                                   float* __restrict__ o,
                                                   float* __restrict__ attn0,
                                                   int Nt, float scale)
{
    __shared__ float Ks[NTOK * HD_];    // swizzled [m][d]
    __shared__ float qs[4][HD_];
    __shared__ float probs[4][256];
    const int bh = blockIdx.x;
    const int b = bh / NH_, h = bh % NH_;
    const int tid = threadIdx.x, lane = tid & 63, w = tid >> 6;
    const float* qkb = qk + (size_t)b * Nt * (2 * C_);
    // stage K (swizzle 16B chunks: chunk' = chunk ^ (m&7))
    for (int e = tid; e < Nt * HD_; e += 256) {
        const int m = e >> 6, d = e & 63;
        Ks[(m << 6) + (((d & 60) ^ ((m & 7) << 2)) | (d & 3))] =
            qkb[(size_t)m * (2 * C_) + C_ + h * HD_ + d];
    }
    __syncthreads();
    const int nIter = (Nt + 3) >> 2;
    const int nkey = (Nt + 63) >> 6;
    const float* vb = vbuf + (size_t)b * Nt * C_ + h * HD_;
    for (int it = 0; it < nIter; ++it) {
        const int q = (it << 2) + w;
        const bool active = (q < Nt);
        if (active) qs[w][lane] = qkb[(size_t)q * (2 * C_) + h * HD_ + lane];
        __syncthreads();
        if (active) {
            const int sw = (lane & 7) << 2;
            float s[4];
            float mx = -1e30f;
#pragma unroll
            for (int t = 0; t < 4; ++t) {
                const int m = lane + (t << 6);
                float sv = -1e30f;
                if (t < nkey && m < Nt) {
                    const float* kr = Ks + (m << 6);
                    float dv = 0.f;
#pragma unroll
                    for (int cc = 0; cc < 16; ++cc) {
                        const float4 kv = *(const float4*)(kr + ((cc << 2) ^ sw));
                        const float4 qv = *(const float4*)(&qs[w][cc << 2]);
                        dv += kv.x * qv.x + kv.y * qv.y + kv.z * qv.z + kv.w * qv.w;
                    }
                    sv = dv * scale;
                }
                s[t] = sv;
                mx = fmaxf(mx, sv);
            }
#pragma unroll
            for (int off = 32; off; off >>= 1) mx = fmaxf(mx, __shfl_xor(mx, off));
            float sum = 0.f;
#pragma unroll
            for (int t = 0; t < 4; ++t) {
                const float e = (s[t] > -1e29f) ? expf(s[t] - mx) : 0.f;
                s[t] = e; sum += e;
            }
#pragma unroll
            for (int off = 32; off; off >>= 1) sum += __shfl_xor(sum, off);
            const float inv = 1.f / sum;
#pragma unroll
            for (int t = 0; t < 4; ++t) {
                const int m = lane + (t << 6);
                const float p = s[t] * inv;
                probs[w][m] = p;                       // zeros for inactive keys
                if (q == 0 && m < Nt) attn0[(size_t)bh * NTOK + m] = p;
            }
        }
        __syncthreads();
        if (active) {
            float accv = 0.f;
            const int nt4 = Nt & ~3;
            for (int m0 = 0; m0 < nt4; m0 += 4) {
                const float4 pv = *(const float4*)&probs[w][m0];
                accv = fmaf(pv.x, vb[(size_t)(m0 + 0) * C_ + lane], accv);
                accv = fmaf(pv.y, vb[(size_t)(m0 + 1) * C_ + lane], accv);
                accv = fmaf(pv.z, vb[(size_t)(m0 + 2) * C_ + lane], accv);
                accv = fmaf(pv.w, vb[(size_t)(m0 + 3) * C_ + lane], accv);
            }
            for (int m = nt4; m < Nt; ++m)
                accv = fmaf(probs[w][m], vb[(size_t)m * C_ + lane], accv);
            o[((size_t)(b * Nt) + q) * C_ + h * HD_ + lane] = accv;
        }
        __syncthreads();
    }
}

// ---------------- cls-attention row: sum over heads of attn[q=0, 1:] ----------------
__global__ __launch_bounds__(256) void row_kernel(const float* __restrict__ attn0,
                                                  float* __restrict__ row, int Nt)
{
    const int b = blockIdx.x, m = threadIdx.x;
    if (m < Nt - 1) {
        float s = 0.f;
#pragma unroll
        for (int h = 0; h < NH_; ++h) s += attn0[((size_t)(b * NH_ + h)) * NTOK + 1 + m];
        row[b * NP_ + m] = s;
    }
}

__global__ __launch_bounds__(256) void cls_ema_kernel(float* cls, const float* __restrict__ row, int first)
{
    const int i = blockIdx.x * 256 + threadIdx.x;
    if (i < B_ * NP_) cls[i] = first ? row[i] : 0.5f * cls[i] + 0.5f * row[i];
}

// ---------------- stable descending rank-sort of cls_attn (196 per batch) ----------------
__global__ __launch_bounds__(256) void rank_kernel(const float* __restrict__ cls,
                                                   int* __restrict__ idx,
                                                   float* __restrict__ sorted,
                                                   float* __restrict__ ssum)
{
    __shared__ float sv[NP_];
    const int b = blockIdx.x, t = threadIdx.x;
    if (t < NP_) sv[t] = cls[b * NP_ + t];
    __syncthreads();
    float val = 0.f; int r = NP_;
    if (t < NP_) {
        val = sv[t];
        r = 0;
        for (int j = 0; j < NP_; ++j) {
            const float vj = sv[j];
            r += (vj > val || (vj == val && j < t)) ? 1 : 0;
        }
        idx[b * NP_ + r] = t;
        sorted[b * NP_ + r] = val;
    }
    const float contrib = (t < NP_ && r >= NKEEP) ? val : 0.f;
    const float tot = blockReduceSum256(contrib);
    if (t == 0) ssum[b] = tot;
}

// ---------------- build xs (B,100,C), fast (B,98,C), rep (B,C) ----------------
__global__ __launch_bounds__(256) void build_xs_kernel(const float* __restrict__ x,
                                                       const int* __restrict__ idx,
                                                       const float* __restrict__ sorted,
                                                       const float* __restrict__ ssum,
                                                       float* __restrict__ xs,
                                                       float* __restrict__ fast,
                                                       float* __restrict__ rep)
{
    const int b = blockIdx.x, t = blockIdx.y, tid = threadIdx.x;
    const float* xb = x + (size_t)b * NTOK * C_;
    if (t == 0) {
#pragma unroll
        for (int j = 0; j < 3; ++j) {
            const int c = tid + j * 256;
            xs[(size_t)b * 100 * C_ + c] = xb[c];
        }
    } else if (t <= NKEEP) {
        const int src = 1 + idx[b * NP_ + (t - 1)];
#pragma unroll
        for (int j = 0; j < 3; ++j) {
            const int c = tid + j * 256;
            xs[((size_t)b * 100 + t) * C_ + c] = xb[(size_t)src * C_ + c];
        }
    } else if (t == NKEEP + 1) {   // rep token (weighted mean of pruned)
        const float inv = 1.f / ssum[b];
        float acc0 = 0.f, acc1 = 0.f, acc2 = 0.f;
        for (int jj = 0; jj < NP_ - NKEEP; ++jj) {
            const int src = 1 + idx[b * NP_ + NKEEP + jj];
            const float wgt = sorted[b * NP_ + NKEEP + jj];
            const float* xr = xb + (size_t)src * C_;
            acc0 = fmaf(xr[tid], wgt, acc0);
            acc1 = fmaf(xr[tid + 256], wgt, acc1);
            acc2 = fmaf(xr[tid + 512], wgt, acc2);
        }
        float* xsr = xs + ((size_t)b * 100 + 99) * C_;
        float* rr = rep + (size_t)b * C_;
        xsr[tid] = acc0 * inv;       rr[tid] = acc0 * inv;
        xsr[tid + 256] = acc1 * inv; rr[tid + 256] = acc1 * inv;
        xsr[tid + 512] = acc2 * inv; rr[tid + 512] = acc2 * inv;
    } else {                       // fast (pruned) tokens
        const int jf = t - (NKEEP + 2);
        const int src = 1 + idx[b * NP_ + NKEEP + jf];
#pragma unroll
        for (int j = 0; j < 3; ++j) {
            const int c = tid + j * 256;
            fast[((size_t)b * (NP_ - NKEEP) + jf) * C_ + c] = xb[(size_t)src * C_ + c];
        }
    }
}

// ---------------- x = concat(xs[:99], fast + 0.5*(xs[99]-rep)) ----------------
__global__ __launch_bounds__(256) void scatter_back_kernel(const float* __restrict__ xs,
                                                           const float* __restrict__ fast,
                                                           const float* __restrict__ rep,
                                                           float* __restrict__ x)
{
    const int b = blockIdx.x, t = blockIdx.y, tid = threadIdx.x;
#pragma unroll
    for (int j = 0; j < 3; ++j) {
        const int c = tid + j * 256;
        float v;
        if (t <= NKEEP)
            v = xs[((size_t)b * 100 + t) * C_ + c];
        else
            v = fast[((size_t)b * (NP_ - NKEEP) + (t - NKEEP - 1)) * C_ + c]
                + 0.5f * (xs[((size_t)b * 100 + 99) * C_ + c] - rep[(size_t)b * C_ + c]);
        x[((size_t)b * NTOK + t) * C_ + c] = v;
    }
}

__global__ __launch_bounds__(256) void cls_prune_update_kernel(float* cls,
                                                               const float* __restrict__ sorted,
                                                               const float* __restrict__ row)
{
    const int i = blockIdx.x * 256 + threadIdx.x;
    if (i < B_ * NP_) {
        const int m = i % NP_;
        const float sv = sorted[i];
        cls[i] = (m < NKEEP) ? 0.5f * sv + 0.5f * row[(i / NP_) * NP_ + m] : sv;
    }
}

// ---------------- host ----------------
extern "C" void kernel_launch(void* const* d_in, const int* in_sizes, int n_in,
                              void* d_out, int out_size, void* d_ws, size_t ws_size,
                              hipStream_t stream)
{
    (void)in_sizes; (void)n_in; (void)out_size;
    const float* x_img   = (const float*)d_in[0];
    const float* cls_tok = (const float*)d_in[1];
    const float* pos     = (const float*)d_in[2];
    const float* patch_w = (const float*)d_in[3];
    const float* patch_b = (const float*)d_in[4];
    const float* ln1_g   = (const float*)d_in[5];
    const float* ln1_b   = (const float*)d_in[6];
    const float* qk_w    = (const float*)d_in[7];
    const float* qk_b    = (const float*)d_in[8];
    const float* v_w     = (const float*)d_in[9];
    const float* v_b     = (const float*)d_in[10];
    const float* proj_w  = (const float*)d_in[11];
    const float* proj_b  = (const float*)d_in[12];
    const float* ln2_g   = (const float*)d_in[13];
    const float* ln2_b   = (const float*)d_in[14];
    const float* fc1_w   = (const float*)d_in[15];
    const float* fc1_b   = (const float*)d_in[16];
    const float* fc2_w   = (const float*)d_in[17];
    const float* fc2_b   = (const float*)d_in[18];
    const float* norm_g  = (const float*)d_in[19];
    const float* norm_b  = (const float*)d_in[20];
    const float* head_w  = (const float*)d_in[21];
    const float* head_b  = (const float*)d_in[22];

    float* W0 = (float*)d_ws;
    size_t off = 0;
    auto alloc = [&](size_t n) { float* r = W0 + off; off += n; return r; };
    float* X    = alloc((size_t)B_ * NTOK * C_);
    float* T    = alloc((size_t)B_ * NTOK * C_);
    float* QK   = alloc((size_t)B_ * NTOK * 2 * C_);
    float* V    = alloc((size_t)B_ * NTOK * C_);
    float* H    = alloc((size_t)B_ * NTOK * 4 * C_);   // also aliases: patches, pemb, attn O
    float* XS   = alloc((size_t)B_ * 100 * C_);
    float* FAST = alloc((size_t)B_ * (NP_ - NKEEP) * C_);
    float* REP  = alloc((size_t)B_ * C_);
    float* ATTN0= alloc((size_t)B_ * NH_ * NTOK);
    float* ROW  = alloc((size_t)B_ * NP_);
    float* CLS  = alloc((size_t)B_ * NP_);
    float* SORT = alloc((size_t)B_ * NP_);
    float* SSUM = alloc((size_t)B_);
    float* T0   = alloc((size_t)B_ * C_);
    int*   IDX  = (int*)alloc((size_t)B_ * NP_);
    if (off * sizeof(float) > ws_size) return;   // not enough scratch: bail (will fail validation loudly)

    float* O = H;                          // attention output aliases H (dead by fc1 time)
    const dim3 blk(256);

    auto runBlock = [&](int i, float* xb, int Nt) {
        const int M = B_ * Nt;
        const dim3 gy((unsigned)((M + 127) / 128));
        ln_kernel<<<M, blk, 0, stream>>>(xb, ln1_g + i * C_, ln1_b + i * C_, T, C_);
        gemm_kernel<<<dim3((2 * C_) / 128, gy.x), blk, 0, stream>>>(
            T, qk_w + (size_t)i * C_ * 2 * C_, qk_b + (size_t)i * 2 * C_, nullptr, QK, M, 2 * C_, C_, 0);
        gemm_kernel<<<dim3(C_ / 128, gy.x), blk, 0, stream>>>(
            T, v_w + (size_t)i * C_ * C_, v_b + (size_t)i * C_, nullptr, V, M, C_, C_, 0);
        attn_kernel<<<B_ * NH_, blk, 0, stream>>>(QK, V, O, ATTN0, Nt, 0.125f);
        row_kernel<<<B_, blk, 0, stream>>>(ATTN0, ROW, Nt);
        gemm_kernel<<<dim3(C_ / 128, gy.x), blk, 0, stream>>>(
            O, proj_w + (size_t)i * C_ * C_, proj_b + (size_t)i * C_, xb, xb, M, C_, C_, 0);
        ln_kernel<<<M, blk, 0, stream>>>(xb, ln2_g + i * C_, ln2_b + i * C_, T, C_);
        gemm_kernel<<<dim3((4 * C_) / 128, gy.x), blk, 0, stream>>>(
            T, fc1_w + (size_t)i * C_ * 4 * C_, fc1_b + (size_t)i * 4 * C_, nullptr, H, M, 4 * C_, C_, 1);
        gemm_kernel<<<dim3(C_ / 128, gy.x), blk, 0, stream>>>(
            H, fc2_w + (size_t)i * 4 * C_ * C_, fc2_b + (size_t)i * C_, xb, xb, M, C_, 4 * C_, 0);
    };

    // ---- patch embedding ----
    float* PATCHES = H;
    float* PEMB = H + (size_t)B_ * NP_ * C_;
    patchify_kernel<<<B_ * NP_, blk, 0, stream>>>(x_img, PATCHES);
    gemm_kernel<<<dim3(C_ / 128, (B_ * NP_ + 127) / 128), blk, 0, stream>>>(
        PATCHES, patch_w, patch_b, nullptr, PEMB, B_ * NP_, C_, C_, 0);
    assemble_x_kernel<<<dim3(B_, NTOK), blk, 0, stream>>>(PEMB, cls_tok, pos, X);

    // ---- 12 transformer blocks ----
    for (int i = 0; i < 12; ++i) {
        if (i < 4) {
            runBlock(i, X, NTOK);
            cls_ema_kernel<<<(B_ * NP_ + 255) / 256, blk, 0, stream>>>(CLS, ROW, i == 0 ? 1 : 0);
        } else {
            rank_kernel<<<B_, blk, 0, stream>>>(CLS, IDX, SORT, SSUM);
            build_xs_kernel<<<dim3(B_, 2 * NP_ - 2 * NKEEP + NKEEP + 2 - (NP_ - NKEEP)), blk, 0, stream>>>(
                X, IDX, SORT, SSUM, XS, FAST, REP);   // grid.y = 100 + 98 = 198
            runBlock(i, XS, 100);
            scatter_back_kernel<<<dim3(B_, NTOK), blk, 0, stream>>>(XS, FAST, REP, X);
            cls_prune_update_kernel<<<(B_ * NP_ + 255) / 256, blk, 0, stream>>>(CLS, SORT, ROW);
        }
    }

    // ---- final LN (token 0 only) + head ----
    ln_kernel<<<B_, blk, 0, stream>>>(X, norm_g, norm_b, T0, (long long)NTOK * C_);
    gemm_kernel<<<dim3((NCLS_ + 127) / 128, 1), blk, 0, stream>>>(
        T0, head_w, head_b, nullptr, (float*)d_out, B_, NCLS_, C_, 0);
}

// Round 2
// 6768.244 us; speedup vs baseline: 3.2510x; 3.2510x over previous
//
#include <hip/hip_runtime.h>
#include <hip/hip_bf16.h>
#include <stdint.h>

#define B_ 32
#define C_ 768
#define NH_ 12
#define HD_ 64
#define NP_ 196
#define NTOK 197
#define NKEEP 98
#define NCLS_ 1000
#define MPAD 6400

typedef __bf16 bf16x8 __attribute__((ext_vector_type(8)));
typedef float f32x4 __attribute__((ext_vector_type(4)));

// ---------------- block reduction (256 threads) ----------------
__device__ __forceinline__ float blockReduceSum256(float v) {
    __shared__ float red[4];
    const int lane = threadIdx.x & 63, w = threadIdx.x >> 6;
#pragma unroll
    for (int off = 32; off; off >>= 1) v += __shfl_down(v, off);
    __syncthreads();
    if (lane == 0) red[w] = v;
    __syncthreads();
    return red[0] + red[1] + red[2] + red[3];
}

// ---------------- async global->LDS (16B per lane) ----------------
__device__ __forceinline__ void gload16(void* lds, const void* g) {
    __builtin_amdgcn_global_load_lds(
        (const __attribute__((address_space(1))) void*)g,
        (__attribute__((address_space(3))) void*)lds,
        16, 0, 0);
}

// ---------------- patchify: (B,3,224,224) -> bf16 (B*196, 768) ----------------
__global__ __launch_bounds__(256) void patchify_kernel(const float* __restrict__ img,
                                                       __hip_bfloat16* __restrict__ patches)
{
    const int bp = blockIdx.x;
    const int b = bp / NP_, p = bp % NP_;
    const int gy = p / 14, gx = p % 14;
    const int tid = threadIdx.x;
#pragma unroll
    for (int j = 0; j < 3; ++j) {
        const int e = tid + j * 256;
        const int c = e >> 8, rem = e & 255, py = rem >> 4, px = rem & 15;
        patches[(size_t)bp * C_ + e] = __float2bfloat16(
            img[(((size_t)b * 3 + c) * 224 + gy * 16 + py) * 224 + gx * 16 + px]);
    }
}

// ---------------- x = concat(cls, pemb) + pos ----------------
__global__ __launch_bounds__(256) void assemble_x_kernel(const float* __restrict__ pemb,
                                                         const float* __restrict__ cls_tok,
                                                         const float* __restrict__ pos,
                                                         float* __restrict__ x)
{
    const int b = blockIdx.x, t = blockIdx.y, tid = threadIdx.x;
#pragma unroll
    for (int j = 0; j < 3; ++j) {
        const int c = tid + j * 256;
        const float v = (t == 0) ? cls_tok[c] : pemb[((size_t)b * NP_ + (t - 1)) * C_ + c];
        x[((size_t)b * NTOK + t) * C_ + c] = v + pos[(size_t)t * C_ + c];
    }
}

// ---------------- layernorm over C=768; bf16 and/or fp32 outputs ----------------
__global__ __launch_bounds__(256) void ln_kernel(const float* __restrict__ x,
                                                 const float* __restrict__ g,
                                                 const float* __restrict__ b,
                                                 __hip_bfloat16* outB, float* outF,
                                                 long long inRowStride)
{
    const int tok = blockIdx.x, tid = threadIdx.x;
    const float* xr = x + (size_t)tok * inRowStride;
    const float v0 = xr[tid], v1 = xr[tid + 256], v2 = xr[tid + 512];
    const float mu = blockReduceSum256(v0 + v1 + v2) * (1.f / C_);
    const float d0 = v0 - mu, d1 = v1 - mu, d2 = v2 - mu;
    const float var = blockReduceSum256(d0 * d0 + d1 * d1 + d2 * d2) * (1.f / C_);
    const float rs = rsqrtf(var + 1e-6f);
    const float o0 = d0 * rs * g[tid]       + b[tid];
    const float o1 = d1 * rs * g[tid + 256] + b[tid + 256];
    const float o2 = d2 * rs * g[tid + 512] + b[tid + 512];
    if (outB) {
        __hip_bfloat16* orow = outB + (size_t)tok * C_;
        orow[tid]       = __float2bfloat16(o0);
        orow[tid + 256] = __float2bfloat16(o1);
        orow[tid + 512] = __float2bfloat16(o2);
    }
    if (outF) {
        float* orow = outF + (size_t)tok * C_;
        orow[tid] = o0; orow[tid + 256] = o1; orow[tid + 512] = o2;
    }
}

// ---------------- weight transpose+convert: fp32 [K][N] -> bf16 [N][K], per layer z ----------------
__global__ __launch_bounds__(256) void transpose_bf16_kernel(const float* __restrict__ W,
                                                             __hip_bfloat16* __restrict__ Wt,
                                                             int K, int N)
{
    __shared__ float tile[32][33];
    const size_t loff = (size_t)blockIdx.z * K * N;
    const int k0 = blockIdx.y << 5, n0 = blockIdx.x << 5;
    const int tid = threadIdx.x;
#pragma unroll
    for (int e = tid; e < 1024; e += 256) {
        const int r = e >> 5, c = e & 31;
        tile[r][c] = W[loff + (size_t)(k0 + r) * N + n0 + c];
    }
    __syncthreads();
#pragma unroll
    for (int e = tid; e < 1024; e += 256) {
        const int r = e >> 5, c = e & 31;
        Wt[loff + (size_t)(n0 + r) * K + k0 + c] = __float2bfloat16(tile[c][r]);
    }
}

// ---------------- bf16 MFMA GEMM (m97 structure): out = act(A @ Bt^T + bias) (+res) ----------------
// A: [>=bm+128][K] bf16, Bt: [N][K] bf16 (pre-transposed weights), K % 32 == 0, N % 128 == 0.
// 128x128 tile, BK=32, 4 waves in 2x2, each wave 4x4 frags of 16x16x32.
__global__ __launch_bounds__(256) void gemm_bf16_kernel(const __hip_bfloat16* __restrict__ A,
                                                        const __hip_bfloat16* __restrict__ Bt,
                                                        const float* __restrict__ bias,
                                                        const float* __restrict__ res,
                                                        float* outF, __hip_bfloat16* outB,
                                                        int K, int N, int act)
{
    __shared__ unsigned short sA[128 * 32];
    __shared__ unsigned short sB[128 * 32];
    const int tid = threadIdx.x;
    const int wv = tid >> 6, ln = tid & 63;
    const int bm = blockIdx.y << 7, bn = blockIdx.x << 7;
    const int wr = wv >> 1, wc = wv & 1;
    const int ln15 = ln & 15, lhi = ln >> 4;

    // staging mapping: wave wv stages rows [wv*16, wv*16+16) (and +64 on 2nd issue)
    const int srow = (wv << 4) + (ln >> 2);
    const int scol = (ln & 3) << 3;
    const __hip_bfloat16* gA = A + (size_t)(bm + srow) * K + scol;
    const __hip_bfloat16* gB = Bt + (size_t)(bn + srow) * K + scol;
    unsigned short* lA = sA + (wv << 9);          // wv*512 elems = wv*1024 B
    unsigned short* lB = sB + (wv << 9);

    f32x4 acc[4][4] = {};
    for (int k0 = 0; k0 < K; k0 += 32) {
        gload16(lA,        gA + k0);
        gload16(lA + 2048, gA + (size_t)64 * K + k0);
        gload16(lB,        gB + k0);
        gload16(lB + 2048, gB + (size_t)64 * K + k0);
        __syncthreads();
        bf16x8 a[4], b[4];
        const bf16x8* SA = (const bf16x8*)sA;
        const bf16x8* SB = (const bf16x8*)sB;
#pragma unroll
        for (int m = 0; m < 4; ++m) a[m] = SA[(((wr << 6) + (m << 4) + ln15) << 2) + lhi];
#pragma unroll
        for (int n = 0; n < 4; ++n) b[n] = SB[(((wc << 6) + (n << 4) + ln15) << 2) + lhi];
#pragma unroll
        for (int m = 0; m < 4; ++m)
#pragma unroll
            for (int n = 0; n < 4; ++n)
                acc[m][n] = __builtin_amdgcn_mfma_f32_16x16x32_bf16(a[m], b[n], acc[m][n], 0, 0, 0);
        __syncthreads();
    }
    // epilogue: D row = (lane>>4)*4 + reg, col = lane&15  [m89-verified]
#pragma unroll
    for (int n = 0; n < 4; ++n) {
        const int gc = bn + (wc << 6) + (n << 4) + ln15;
        const float bv = bias ? bias[gc] : 0.f;
#pragma unroll
        for (int m = 0; m < 4; ++m) {
            const int gr0 = bm + (wr << 6) + (m << 4) + (lhi << 2);
            f32x4 v = acc[m][n];
#pragma unroll
            for (int r = 0; r < 4; ++r) {
                const size_t o = (size_t)(gr0 + r) * N + gc;
                float x = v[r] + bv;
                if (act == 1) x = 0.5f * x * (1.f + erff(x * 0.70710678118654752f));
                if (res) x += res[o];
                if (outF) outF[o] = x;
                if (outB) outB[o] = __float2bfloat16(x);
            }
        }
    }
}

// ---------------- fp32 GEMM (head only: M=32, N=1000) ----------------
__global__ __launch_bounds__(256) void gemm_f32_kernel(const float* __restrict__ A,
                                                       const float* __restrict__ W,
                                                       const float* __restrict__ bias,
                                                       const float* res, float* Cout,
                                                       int M, int N, int K, int act)
{
    __shared__ float As[16][132];
    __shared__ float Ws[16][128];
    const int tid = threadIdx.x;
    const int bm = blockIdx.y << 7;
    const int bn = blockIdx.x << 7;
    const int tx = tid & 15, ty = tid >> 4;
    const int arow = tid >> 1, acol = (tid & 1) << 3;
    const int wrow = tid >> 4, wcol = (tid & 15) << 3;
    float acc[8][8] = {};
    for (int k0 = 0; k0 < K; k0 += 16) {
        float4 a0 = make_float4(0.f, 0.f, 0.f, 0.f), a1 = a0;
        if (bm + arow < M) {
            const float* ap = A + (size_t)(bm + arow) * K + k0 + acol;
            a0 = *(const float4*)ap;
            a1 = *(const float4*)(ap + 4);
        }
        As[acol + 0][arow] = a0.x; As[acol + 1][arow] = a0.y;
        As[acol + 2][arow] = a0.z; As[acol + 3][arow] = a0.w;
        As[acol + 4][arow] = a1.x; As[acol + 5][arow] = a1.y;
        As[acol + 6][arow] = a1.z; As[acol + 7][arow] = a1.w;
        {
            const int gc = bn + wcol;
            const float* wp = W + (size_t)(k0 + wrow) * N + gc;
            float4 w0, w1;
            if (gc + 7 < N) { w0 = *(const float4*)wp; w1 = *(const float4*)(wp + 4); }
            else {
                float tmp[8];
#pragma unroll
                for (int j = 0; j < 8; ++j) tmp[j] = (gc + j < N) ? wp[j] : 0.f;
                w0 = make_float4(tmp[0], tmp[1], tmp[2], tmp[3]);
                w1 = make_float4(tmp[4], tmp[5], tmp[6], tmp[7]);
            }
            *(float4*)&Ws[wrow][wcol]     = w0;
            *(float4*)&Ws[wrow][wcol + 4] = w1;
        }
        __syncthreads();
#pragma unroll
        for (int k = 0; k < 16; ++k) {
            float a[8], bb[8];
#pragma unroll
            for (int i = 0; i < 8; ++i) a[i] = As[k][ty + (i << 4)];
#pragma unroll
            for (int j = 0; j < 8; ++j) bb[j] = Ws[k][tx + (j << 4)];
#pragma unroll
            for (int i = 0; i < 8; ++i)
#pragma unroll
                for (int j = 0; j < 8; ++j)
                    acc[i][j] = fmaf(a[i], bb[j], acc[i][j]);
        }
        __syncthreads();
    }
#pragma unroll
    for (int i = 0; i < 8; ++i) {
        const int gr = bm + ty + (i << 4);
        if (gr >= M) continue;
#pragma unroll
        for (int j = 0; j < 8; ++j) {
            const int gc = bn + tx + (j << 4);
            if (gc >= N) continue;
            float v = acc[i][j];
            if (bias) v += bias[gc];
            if (act == 1) v = 0.5f * v * (1.f + erff(v * 0.70710678118654752f));
            if (res) v += res[(size_t)gr * N + gc];
            Cout[(size_t)gr * N + gc] = v;
        }
    }
}

// ---------------- attention: one block per (b,h), 4 waves, wave-per-query ----------------
__global__ __launch_bounds__(256) void attn_kernel(const float* __restrict__ qk,
                                                   const float* __restrict__ vbuf,
                                                   __hip_bfloat16* __restrict__ o,
                                                   float* __restrict__ attn0,
                                                   int Nt, float scale)
{
    __shared__ float Ks[NTOK * HD_];
    __shared__ float qs[4][HD_];
    __shared__ float probs[4][256];
    const int bh = blockIdx.x;
    const int b = bh / NH_, h = bh % NH_;
    const int tid = threadIdx.x, lane = tid & 63, w = tid >> 6;
    const float* qkb = qk + (size_t)b * Nt * (2 * C_);
    for (int e = tid; e < Nt * HD_; e += 256) {
        const int m = e >> 6, d = e & 63;
        Ks[(m << 6) + (((d & 60) ^ ((m & 7) << 2)) | (d & 3))] =
            qkb[(size_t)m * (2 * C_) + C_ + h * HD_ + d];
    }
    __syncthreads();
    const int nIter = (Nt + 3) >> 2;
    const int nkey = (Nt + 63) >> 6;
    const float* vb = vbuf + (size_t)b * Nt * C_ + h * HD_;
    for (int it = 0; it < nIter; ++it) {
        const int q = (it << 2) + w;
        const bool active = (q < Nt);
        if (active) qs[w][lane] = qkb[(size_t)q * (2 * C_) + h * HD_ + lane];
        __syncthreads();
        if (active) {
            const int sw = (lane & 7) << 2;
            float s[4];
            float mx = -1e30f;
#pragma unroll
            for (int t = 0; t < 4; ++t) {
                const int m = lane + (t << 6);
                float sv = -1e30f;
                if (t < nkey && m < Nt) {
                    const float* kr = Ks + (m << 6);
                    float dv = 0.f;
#pragma unroll
                    for (int cc = 0; cc < 16; ++cc) {
                        const float4 kv = *(const float4*)(kr + ((cc << 2) ^ sw));
                        const float4 qv = *(const float4*)(&qs[w][cc << 2]);
                        dv += kv.x * qv.x + kv.y * qv.y + kv.z * qv.z + kv.w * qv.w;
                    }
                    sv = dv * scale;
                }
                s[t] = sv;
                mx = fmaxf(mx, sv);
            }
#pragma unroll
            for (int off = 32; off; off >>= 1) mx = fmaxf(mx, __shfl_xor(mx, off));
            float sum = 0.f;
#pragma unroll
            for (int t = 0; t < 4; ++t) {
                const float e = (s[t] > -1e29f) ? expf(s[t] - mx) : 0.f;
                s[t] = e; sum += e;
            }
#pragma unroll
            for (int off = 32; off; off >>= 1) sum += __shfl_xor(sum, off);
            const float inv = 1.f / sum;
#pragma unroll
            for (int t = 0; t < 4; ++t) {
                const int m = lane + (t << 6);
                const float p = s[t] * inv;
                probs[w][m] = p;
                if (q == 0 && m < Nt) attn0[(size_t)bh * NTOK + m] = p;
            }
        }
        __syncthreads();
        if (active) {
            float accv = 0.f;
            const int nt4 = Nt & ~3;
            for (int m0 = 0; m0 < nt4; m0 += 4) {
                const float4 pv = *(const float4*)&probs[w][m0];
                accv = fmaf(pv.x, vb[(size_t)(m0 + 0) * C_ + lane], accv);
                accv = fmaf(pv.y, vb[(size_t)(m0 + 1) * C_ + lane], accv);
                accv = fmaf(pv.z, vb[(size_t)(m0 + 2) * C_ + lane], accv);
                accv = fmaf(pv.w, vb[(size_t)(m0 + 3) * C_ + lane], accv);
            }
            for (int m = nt4; m < Nt; ++m)
                accv = fmaf(probs[w][m], vb[(size_t)m * C_ + lane], accv);
            o[((size_t)(b * Nt) + q) * C_ + h * HD_ + lane] = __float2bfloat16(accv);
        }
        __syncthreads();
    }
}

// ---------------- cls-attention row ----------------
__global__ __launch_bounds__(256) void row_kernel(const float* __restrict__ attn0,
                                                  float* __restrict__ row, int Nt)
{
    const int b = blockIdx.x, m = threadIdx.x;
    if (m < Nt - 1) {
        float s = 0.f;
#pragma unroll
        for (int h = 0; h < NH_; ++h) s += attn0[((size_t)(b * NH_ + h)) * NTOK + 1 + m];
        row[b * NP_ + m] = s;
    }
}

__global__ __launch_bounds__(256) void cls_ema_kernel(float* cls, const float* __restrict__ row, int first)
{
    const int i = blockIdx.x * 256 + threadIdx.x;
    if (i < B_ * NP_) cls[i] = first ? row[i] : 0.5f * cls[i] + 0.5f * row[i];
}

// ---------------- stable descending rank-sort of cls_attn ----------------
__global__ __launch_bounds__(256) void rank_kernel(const float* __restrict__ cls,
                                                   int* __restrict__ idx,
                                                   float* __restrict__ sorted,
                                                   float* __restrict__ ssum)
{
    __shared__ float sv[NP_];
    const int b = blockIdx.x, t = threadIdx.x;
    if (t < NP_) sv[t] = cls[b * NP_ + t];
    __syncthreads();
    float val = 0.f; int r = NP_;
    if (t < NP_) {
        val = sv[t];
        r = 0;
        for (int j = 0; j < NP_; ++j) {
            const float vj = sv[j];
            r += (vj > val || (vj == val && j < t)) ? 1 : 0;
        }
        idx[b * NP_ + r] = t;
        sorted[b * NP_ + r] = val;
    }
    const float contrib = (t < NP_ && r >= NKEEP) ? val : 0.f;
    const float tot = blockReduceSum256(contrib);
    if (t == 0) ssum[b] = tot;
}

// ---------------- build xs / fast / rep ----------------
__global__ __launch_bounds__(256) void build_xs_kernel(const float* __restrict__ x,
                                                       const int* __restrict__ idx,
                                                       const float* __restrict__ sorted,
                                                       const float* __restrict__ ssum,
                                                       float* __restrict__ xs,
                                                       float* __restrict__ fast,
                                                       float* __restrict__ rep)
{
    const int b = blockIdx.x, t = blockIdx.y, tid = threadIdx.x;
    const float* xb = x + (size_t)b * NTOK * C_;
    if (t == 0) {
#pragma unroll
        for (int j = 0; j < 3; ++j) {
            const int c = tid + j * 256;
            xs[(size_t)b * 100 * C_ + c] = xb[c];
        }
    } else if (t <= NKEEP) {
        const int src = 1 + idx[b * NP_ + (t - 1)];
#pragma unroll
        for (int j = 0; j < 3; ++j) {
            const int c = tid + j * 256;
            xs[((size_t)b * 100 + t) * C_ + c] = xb[(size_t)src * C_ + c];
        }
    } else if (t == NKEEP + 1) {
        const float inv = 1.f / ssum[b];
        float acc0 = 0.f, acc1 = 0.f, acc2 = 0.f;
        for (int jj = 0; jj < NP_ - NKEEP; ++jj) {
            const int src = 1 + idx[b * NP_ + NKEEP + jj];
            const float wgt = sorted[b * NP_ + NKEEP + jj];
            const float* xr = xb + (size_t)src * C_;
            acc0 = fmaf(xr[tid], wgt, acc0);
            acc1 = fmaf(xr[tid + 256], wgt, acc1);
            acc2 = fmaf(xr[tid + 512], wgt, acc2);
        }
        float* xsr = xs + ((size_t)b * 100 + 99) * C_;
        float* rr = rep + (size_t)b * C_;
        xsr[tid] = acc0 * inv;       rr[tid] = acc0 * inv;
        xsr[tid + 256] = acc1 * inv; rr[tid + 256] = acc1 * inv;
        xsr[tid + 512] = acc2 * inv; rr[tid + 512] = acc2 * inv;
    } else {
        const int jf = t - (NKEEP + 2);
        const int src = 1 + idx[b * NP_ + NKEEP + jf];
#pragma unroll
        for (int j = 0; j < 3; ++j) {
            const int c = tid + j * 256;
            fast[((size_t)b * (NP_ - NKEEP) + jf) * C_ + c] = xb[(size_t)src * C_ + c];
        }
    }
}

__global__ __launch_bounds__(256) void scatter_back_kernel(const float* __restrict__ xs,
                                                           const float* __restrict__ fast,
                                                           const float* __restrict__ rep,
                                                           float* __restrict__ x)
{
    const int b = blockIdx.x, t = blockIdx.y, tid = threadIdx.x;
#pragma unroll
    for (int j = 0; j < 3; ++j) {
        const int c = tid + j * 256;
        float v;
        if (t <= NKEEP)
            v = xs[((size_t)b * 100 + t) * C_ + c];
        else
            v = fast[((size_t)b * (NP_ - NKEEP) + (t - NKEEP - 1)) * C_ + c]
                + 0.5f * (xs[((size_t)b * 100 + 99) * C_ + c] - rep[(size_t)b * C_ + c]);
        x[((size_t)b * NTOK + t) * C_ + c] = v;
    }
}

__global__ __launch_bounds__(256) void cls_prune_update_kernel(float* cls,
                                                               const float* __restrict__ sorted,
                                                               const float* __restrict__ row)
{
    const int i = blockIdx.x * 256 + threadIdx.x;
    if (i < B_ * NP_) {
        const int m = i % NP_;
        const float sv = sorted[i];
        cls[i] = (m < NKEEP) ? 0.5f * sv + 0.5f * row[(i / NP_) * NP_ + m] : sv;
    }
}

// ---------------- host ----------------
extern "C" void kernel_launch(void* const* d_in, const int* in_sizes, int n_in,
                              void* d_out, int out_size, void* d_ws, size_t ws_size,
                              hipStream_t stream)
{
    (void)in_sizes; (void)n_in; (void)out_size;
    const float* x_img   = (const float*)d_in[0];
    const float* cls_tok = (const float*)d_in[1];
    const float* pos     = (const float*)d_in[2];
    const float* patch_w = (const float*)d_in[3];
    const float* patch_b = (const float*)d_in[4];
    const float* ln1_g   = (const float*)d_in[5];
    const float* ln1_b   = (const float*)d_in[6];
    const float* qk_w    = (const float*)d_in[7];
    const float* qk_b    = (const float*)d_in[8];
    const float* v_w     = (const float*)d_in[9];
    const float* v_b     = (const float*)d_in[10];
    const float* proj_w  = (const float*)d_in[11];
    const float* proj_b  = (const float*)d_in[12];
    const float* ln2_g   = (const float*)d_in[13];
    const float* ln2_b   = (const float*)d_in[14];
    const float* fc1_w   = (const float*)d_in[15];
    const float* fc1_b   = (const float*)d_in[16];
    const float* fc2_w   = (const float*)d_in[17];
    const float* fc2_b   = (const float*)d_in[18];
    const float* norm_g  = (const float*)d_in[19];
    const float* norm_b  = (const float*)d_in[20];
    const float* head_w  = (const float*)d_in[21];
    const float* head_b  = (const float*)d_in[22];

    char* base = (char*)d_ws;
    size_t off = 0;
    auto alloc = [&](size_t bytes) -> void* {
        void* p = base + off; off = (off + bytes + 255) & ~(size_t)255; return p;
    };
    float* X    = (float*)alloc((size_t)MPAD * C_ * 4);
    __hip_bfloat16* Tb = (__hip_bfloat16*)alloc((size_t)MPAD * C_ * 2);
    float* QK   = (float*)alloc((size_t)MPAD * 2 * C_ * 4);
    float* V    = (float*)alloc((size_t)MPAD * C_ * 4);
    __hip_bfloat16* Hb = (__hip_bfloat16*)alloc((size_t)MPAD * 4 * C_ * 2);
    float* XS   = (float*)alloc((size_t)3200 * C_ * 4);
    float* FAST = (float*)alloc((size_t)B_ * (NP_ - NKEEP) * C_ * 4);
    float* REP  = (float*)alloc((size_t)B_ * C_ * 4);
    float* ATTN0= (float*)alloc((size_t)B_ * NH_ * NTOK * 4);
    float* ROW  = (float*)alloc((size_t)B_ * NP_ * 4);
    float* CLS  = (float*)alloc((size_t)B_ * NP_ * 4);
    float* SORT = (float*)alloc((size_t)B_ * NP_ * 4);
    float* SSUM = (float*)alloc((size_t)B_ * 4);
    float* T0   = (float*)alloc((size_t)B_ * C_ * 4);
    int*   IDX  = (int*)alloc((size_t)B_ * NP_ * 4);
    __hip_bfloat16* WTpatch = (__hip_bfloat16*)alloc((size_t)C_ * C_ * 2);
    __hip_bfloat16* WTqk    = (__hip_bfloat16*)alloc((size_t)12 * C_ * 2 * C_ * 2);
    __hip_bfloat16* WTv     = (__hip_bfloat16*)alloc((size_t)12 * C_ * C_ * 2);
    __hip_bfloat16* WTproj  = (__hip_bfloat16*)alloc((size_t)12 * C_ * C_ * 2);
    __hip_bfloat16* WTfc1   = (__hip_bfloat16*)alloc((size_t)12 * C_ * 4 * C_ * 2);
    __hip_bfloat16* WTfc2   = (__hip_bfloat16*)alloc((size_t)12 * 4 * C_ * C_ * 2);
    if (off > ws_size) return;   // insufficient scratch -> loud validation failure

    __hip_bfloat16* Ob     = Hb;   // attn output aliases Hb (dead by fc1 time)
    __hip_bfloat16* PATCH  = Hb;   // patch-phase alias
    float*          PEMB   = QK;   // patch-phase alias

    const dim3 blk(256);

    // ---- weight transpose+convert (fp32 [K][N] -> bf16 [N][K]) ----
    transpose_bf16_kernel<<<dim3(C_ / 32, C_ / 32, 1), blk, 0, stream>>>(patch_w, WTpatch, C_, C_);
    transpose_bf16_kernel<<<dim3(2 * C_ / 32, C_ / 32, 12), blk, 0, stream>>>(qk_w, WTqk, C_, 2 * C_);
    transpose_bf16_kernel<<<dim3(C_ / 32, C_ / 32, 12), blk, 0, stream>>>(v_w, WTv, C_, C_);
    transpose_bf16_kernel<<<dim3(C_ / 32, C_ / 32, 12), blk, 0, stream>>>(proj_w, WTproj, C_, C_);
    transpose_bf16_kernel<<<dim3(4 * C_ / 32, C_ / 32, 12), blk, 0, stream>>>(fc1_w, WTfc1, C_, 4 * C_);
    transpose_bf16_kernel<<<dim3(C_ / 32, 4 * C_ / 32, 12), blk, 0, stream>>>(fc2_w, WTfc2, 4 * C_, C_);

    auto runBlock = [&](int i, float* xb, int Nt) {
        const int M = B_ * Nt;
        const int mt = (M + 127) >> 7;
        ln_kernel<<<M, blk, 0, stream>>>(xb, ln1_g + i * C_, ln1_b + i * C_, Tb, nullptr, C_);
        gemm_bf16_kernel<<<dim3(12, mt), blk, 0, stream>>>(
            Tb, WTqk + (size_t)i * 2 * C_ * C_, qk_b + (size_t)i * 2 * C_, nullptr, QK, nullptr, C_, 2 * C_, 0);
        gemm_bf16_kernel<<<dim3(6, mt), blk, 0, stream>>>(
            Tb, WTv + (size_t)i * C_ * C_, v_b + (size_t)i * C_, nullptr, V, nullptr, C_, C_, 0);
        attn_kernel<<<B_ * NH_, blk, 0, stream>>>(QK, V, Ob, ATTN0, Nt, 0.125f);
        row_kernel<<<B_, blk, 0, stream>>>(ATTN0, ROW, Nt);
        gemm_bf16_kernel<<<dim3(6, mt), blk, 0, stream>>>(
            Ob, WTproj + (size_t)i * C_ * C_, proj_b + (size_t)i * C_, xb, xb, nullptr, C_, C_, 0);
        ln_kernel<<<M, blk, 0, stream>>>(xb, ln2_g + i * C_, ln2_b + i * C_, Tb, nullptr, C_);
        gemm_bf16_kernel<<<dim3(24, mt), blk, 0, stream>>>(
            Tb, WTfc1 + (size_t)i * C_ * 4 * C_, fc1_b + (size_t)i * 4 * C_, nullptr, nullptr, Hb, C_, 4 * C_, 1);
        gemm_bf16_kernel<<<dim3(6, mt), blk, 0, stream>>>(
            Hb, WTfc2 + (size_t)i * 4 * C_ * C_, fc2_b + (size_t)i * C_, xb, xb, nullptr, 4 * C_, C_, 0);
    };

    // ---- patch embedding ----
    patchify_kernel<<<B_ * NP_, blk, 0, stream>>>(x_img, PATCH);
    gemm_bf16_kernel<<<dim3(6, 49), blk, 0, stream>>>(
        PATCH, WTpatch, patch_b, nullptr, PEMB, nullptr, C_, C_, 0);
    assemble_x_kernel<<<dim3(B_, NTOK), blk, 0, stream>>>(PEMB, cls_tok, pos, X);

    // ---- 12 transformer blocks ----
    for (int i = 0; i < 12; ++i) {
        if (i < 4) {
            runBlock(i, X, NTOK);
            cls_ema_kernel<<<(B_ * NP_ + 255) / 256, blk, 0, stream>>>(CLS, ROW, i == 0 ? 1 : 0);
        } else {
            rank_kernel<<<B_, blk, 0, stream>>>(CLS, IDX, SORT, SSUM);
            build_xs_kernel<<<dim3(B_, 198), blk, 0, stream>>>(X, IDX, SORT, SSUM, XS, FAST, REP);
            runBlock(i, XS, 100);
            scatter_back_kernel<<<dim3(B_, NTOK), blk, 0, stream>>>(XS, FAST, REP, X);
            cls_prune_update_kernel<<<(B_ * NP_ + 255) / 256, blk, 0, stream>>>(CLS, SORT, ROW);
        }
    }

    // ---- final LN (token 0 only) + head (fp32) ----
    ln_kernel<<<B_, blk, 0, stream>>>(X, norm_g, norm_b, nullptr, T0, (long long)NTOK * C_);
    gemm_f32_kernel<<<dim3((NCLS_ + 127) / 128, 1), blk, 0, stream>>>(
        T0, head_w, head_b, nullptr, (float*)d_out, B_, NCLS_, C_, 0);
}

// Round 3
// 4361.716 us; speedup vs baseline: 5.0447x; 1.5517x over previous
//
#include <hip/hip_runtime.h>
#include <hip/hip_bf16.h>
#include <stdint.h>

#define B_ 32
#define C_ 768
#define NH_ 12
#define HD_ 64
#define NP_ 196
#define NTOK 197
#define NKEEP 98
#define NCLS_ 1000
#define MPAD 6400

typedef __bf16 bf16x8 __attribute__((ext_vector_type(8)));
typedef float f32x4 __attribute__((ext_vector_type(4)));

// ---------------- block reduction (256 threads) ----------------
__device__ __forceinline__ float blockReduceSum256(float v) {
    __shared__ float red[4];
    const int lane = threadIdx.x & 63, w = threadIdx.x >> 6;
#pragma unroll
    for (int off = 32; off; off >>= 1) v += __shfl_down(v, off);
    __syncthreads();
    if (lane == 0) red[w] = v;
    __syncthreads();
    return red[0] + red[1] + red[2] + red[3];
}

// ---------------- async global->LDS (16B per lane) ----------------
__device__ __forceinline__ void gload16(void* lds, const void* g) {
    __builtin_amdgcn_global_load_lds(
        (const __attribute__((address_space(1))) void*)g,
        (__attribute__((address_space(3))) void*)lds,
        16, 0, 0);
}

// ---------------- patchify: (B,3,224,224) -> bf16 (B*196, 768) ----------------
__global__ __launch_bounds__(256) void patchify_kernel(const float* __restrict__ img,
                                                       __hip_bfloat16* __restrict__ patches)
{
    const int bp = blockIdx.x;
    const int b = bp / NP_, p = bp % NP_;
    const int gy = p / 14, gx = p % 14;
    const int tid = threadIdx.x;
#pragma unroll
    for (int j = 0; j < 3; ++j) {
        const int e = tid + j * 256;
        const int c = e >> 8, rem = e & 255, py = rem >> 4, px = rem & 15;
        patches[(size_t)bp * C_ + e] = __float2bfloat16(
            img[(((size_t)b * 3 + c) * 224 + gy * 16 + py) * 224 + gx * 16 + px]);
    }
}

// ---------------- x = concat(cls, pemb) + pos ----------------
__global__ __launch_bounds__(256) void assemble_x_kernel(const float* __restrict__ pemb,
                                                         const float* __restrict__ cls_tok,
                                                         const float* __restrict__ pos,
                                                         float* __restrict__ x)
{
    const int b = blockIdx.x, t = blockIdx.y, tid = threadIdx.x;
#pragma unroll
    for (int j = 0; j < 3; ++j) {
        const int c = tid + j * 256;
        const float v = (t == 0) ? cls_tok[c] : pemb[((size_t)b * NP_ + (t - 1)) * C_ + c];
        x[((size_t)b * NTOK + t) * C_ + c] = v + pos[(size_t)t * C_ + c];
    }
}

// ---------------- layernorm over C=768; bf16 and/or fp32 outputs ----------------
__global__ __launch_bounds__(256) void ln_kernel(const float* __restrict__ x,
                                                 const float* __restrict__ g,
                                                 const float* __restrict__ b,
                                                 __hip_bfloat16* outB, float* outF,
                                                 long long inRowStride)
{
    const int tok = blockIdx.x, tid = threadIdx.x;
    const float* xr = x + (size_t)tok * inRowStride;
    const float v0 = xr[tid], v1 = xr[tid + 256], v2 = xr[tid + 512];
    const float mu = blockReduceSum256(v0 + v1 + v2) * (1.f / C_);
    const float d0 = v0 - mu, d1 = v1 - mu, d2 = v2 - mu;
    const float var = blockReduceSum256(d0 * d0 + d1 * d1 + d2 * d2) * (1.f / C_);
    const float rs = rsqrtf(var + 1e-6f);
    const float o0 = d0 * rs * g[tid]       + b[tid];
    const float o1 = d1 * rs * g[tid + 256] + b[tid + 256];
    const float o2 = d2 * rs * g[tid + 512] + b[tid + 512];
    if (outB) {
        __hip_bfloat16* orow = outB + (size_t)tok * C_;
        orow[tid]       = __float2bfloat16(o0);
        orow[tid + 256] = __float2bfloat16(o1);
        orow[tid + 512] = __float2bfloat16(o2);
    }
    if (outF) {
        float* orow = outF + (size_t)tok * C_;
        orow[tid] = o0; orow[tid + 256] = o1; orow[tid + 512] = o2;
    }
}

// ---------------- weight transpose+convert: fp32 [K][N] -> bf16 [N][K] ----------------
__global__ __launch_bounds__(256) void transpose_bf16_kernel(const float* __restrict__ W,
                                                             __hip_bfloat16* __restrict__ Wt,
                                                             int K, int N)
{
    __shared__ float tile[32][33];
    const size_t loff = (size_t)blockIdx.z * K * N;
    const int k0 = blockIdx.y << 5, n0 = blockIdx.x << 5;
    const int tid = threadIdx.x;
#pragma unroll
    for (int e = tid; e < 1024; e += 256) {
        const int r = e >> 5, c = e & 31;
        tile[r][c] = W[loff + (size_t)(k0 + r) * N + n0 + c];
    }
    __syncthreads();
#pragma unroll
    for (int e = tid; e < 1024; e += 256) {
        const int r = e >> 5, c = e & 31;
        Wt[loff + (size_t)(n0 + r) * K + k0 + c] = __float2bfloat16(tile[c][r]);
    }
}

// ---------------- bf16 MFMA GEMM (m97 structure) ----------------
__global__ __launch_bounds__(256) void gemm_bf16_kernel(const __hip_bfloat16* __restrict__ A,
                                                        const __hip_bfloat16* __restrict__ Bt,
                                                        const float* __restrict__ bias,
                                                        const float* __restrict__ res,
                                                        float* outF, __hip_bfloat16* outB,
                                                        int K, int N, int act)
{
    __shared__ unsigned short sA[128 * 32];
    __shared__ unsigned short sB[128 * 32];
    const int tid = threadIdx.x;
    const int wv = tid >> 6, ln = tid & 63;
    const int bm = blockIdx.y << 7, bn = blockIdx.x << 7;
    const int wr = wv >> 1, wc = wv & 1;
    const int ln15 = ln & 15, lhi = ln >> 4;

    const int srow = (wv << 4) + (ln >> 2);
    const int scol = (ln & 3) << 3;
    const __hip_bfloat16* gA = A + (size_t)(bm + srow) * K + scol;
    const __hip_bfloat16* gB = Bt + (size_t)(bn + srow) * K + scol;
    unsigned short* lA = sA + (wv << 9);
    unsigned short* lB = sB + (wv << 9);

    f32x4 acc[4][4] = {};
    for (int k0 = 0; k0 < K; k0 += 32) {
        gload16(lA,        gA + k0);
        gload16(lA + 2048, gA + (size_t)64 * K + k0);
        gload16(lB,        gB + k0);
        gload16(lB + 2048, gB + (size_t)64 * K + k0);
        __syncthreads();
        bf16x8 a[4], b[4];
        const bf16x8* SA = (const bf16x8*)sA;
        const bf16x8* SB = (const bf16x8*)sB;
#pragma unroll
        for (int m = 0; m < 4; ++m) a[m] = SA[(((wr << 6) + (m << 4) + ln15) << 2) + lhi];
#pragma unroll
        for (int n = 0; n < 4; ++n) b[n] = SB[(((wc << 6) + (n << 4) + ln15) << 2) + lhi];
#pragma unroll
        for (int m = 0; m < 4; ++m)
#pragma unroll
            for (int n = 0; n < 4; ++n)
                acc[m][n] = __builtin_amdgcn_mfma_f32_16x16x32_bf16(a[m], b[n], acc[m][n], 0, 0, 0);
        __syncthreads();
    }
#pragma unroll
    for (int n = 0; n < 4; ++n) {
        const int gc = bn + (wc << 6) + (n << 4) + ln15;
        const float bv = bias ? bias[gc] : 0.f;
#pragma unroll
        for (int m = 0; m < 4; ++m) {
            const int gr0 = bm + (wr << 6) + (m << 4) + (lhi << 2);
            f32x4 v = acc[m][n];
#pragma unroll
            for (int r = 0; r < 4; ++r) {
                const size_t o = (size_t)(gr0 + r) * N + gc;
                float x = v[r] + bv;
                if (act == 1) x = 0.5f * x * (1.f + erff(x * 0.70710678118654752f));
                if (res) x += res[o];
                if (outF) outF[o] = x;
                if (outB) outB[o] = __float2bfloat16(x);
            }
        }
    }
}

// ---------------- fp32 GEMM (head only) ----------------
__global__ __launch_bounds__(256) void gemm_f32_kernel(const float* __restrict__ A,
                                                       const float* __restrict__ W,
                                                       const float* __restrict__ bias,
                                                       const float* res, float* Cout,
                                                       int M, int N, int K, int act)
{
    __shared__ float As[16][132];
    __shared__ float Ws[16][128];
    const int tid = threadIdx.x;
    const int bm = blockIdx.y << 7;
    const int bn = blockIdx.x << 7;
    const int tx = tid & 15, ty = tid >> 4;
    const int arow = tid >> 1, acol = (tid & 1) << 3;
    const int wrow = tid >> 4, wcol = (tid & 15) << 3;
    float acc[8][8] = {};
    for (int k0 = 0; k0 < K; k0 += 16) {
        float4 a0 = make_float4(0.f, 0.f, 0.f, 0.f), a1 = a0;
        if (bm + arow < M) {
            const float* ap = A + (size_t)(bm + arow) * K + k0 + acol;
            a0 = *(const float4*)ap;
            a1 = *(const float4*)(ap + 4);
        }
        As[acol + 0][arow] = a0.x; As[acol + 1][arow] = a0.y;
        As[acol + 2][arow] = a0.z; As[acol + 3][arow] = a0.w;
        As[acol + 4][arow] = a1.x; As[acol + 5][arow] = a1.y;
        As[acol + 6][arow] = a1.z; As[acol + 7][arow] = a1.w;
        {
            const int gc = bn + wcol;
            const float* wp = W + (size_t)(k0 + wrow) * N + gc;
            float4 w0, w1;
            if (gc + 7 < N) { w0 = *(const float4*)wp; w1 = *(const float4*)(wp + 4); }
            else {
                float tmp[8];
#pragma unroll
                for (int j = 0; j < 8; ++j) tmp[j] = (gc + j < N) ? wp[j] : 0.f;
                w0 = make_float4(tmp[0], tmp[1], tmp[2], tmp[3]);
                w1 = make_float4(tmp[4], tmp[5], tmp[6], tmp[7]);
            }
            *(float4*)&Ws[wrow][wcol]     = w0;
            *(float4*)&Ws[wrow][wcol + 4] = w1;
        }
        __syncthreads();
#pragma unroll
        for (int k = 0; k < 16; ++k) {
            float a[8], bb[8];
#pragma unroll
            for (int i = 0; i < 8; ++i) a[i] = As[k][ty + (i << 4)];
#pragma unroll
            for (int j = 0; j < 8; ++j) bb[j] = Ws[k][tx + (j << 4)];
#pragma unroll
            for (int i = 0; i < 8; ++i)
#pragma unroll
                for (int j = 0; j < 8; ++j)
                    acc[i][j] = fmaf(a[i], bb[j], acc[i][j]);
        }
        __syncthreads();
    }
#pragma unroll
    for (int i = 0; i < 8; ++i) {
        const int gr = bm + ty + (i << 4);
        if (gr >= M) continue;
#pragma unroll
        for (int j = 0; j < 8; ++j) {
            const int gc = bn + tx + (j << 4);
            if (gc >= N) continue;
            float v = acc[i][j];
            if (bias) v += bias[gc];
            if (act == 1) v = 0.5f * v * (1.f + erff(v * 0.70710678118654752f));
            if (res) v += res[(size_t)gr * N + gc];
            Cout[(size_t)gr * N + gc] = v;
        }
    }
}

// ---------------- MFMA attention ----------------
// Block = (b*NH+h, qtile). 4 waves x 16 queries. K,V staged in LDS (bf16),
// swapped QK^T (mfma(K,Q)) -> lane owns score row for its query; softmax with
// 2 shuffles; P packed to LDS (aliases K); PV = mfma(P, V^T).
template<int NT16>
__global__ __launch_bounds__(256) void attn_mfma_kernel(const __hip_bfloat16* __restrict__ qkb,
                                                        const __hip_bfloat16* __restrict__ vbuf,
                                                        __hip_bfloat16* __restrict__ o,
                                                        float* __restrict__ attn0,
                                                        int Nt)
{
    constexpr int NPAD = NT16 * 16;
    constexpr int ROWB = NPAD * 2;                 // V^T / P row bytes
    constexpr int VSW = (((NPAD / 8) & 7) == 0) ? 7 : 3;
    __shared__ unsigned short sK[NPAD * 64];       // [key][d] 128B rows, chunk^=(key&7); P aliases after S
    __shared__ unsigned short sV[64 * NPAD];       // V^T [d][key], chunk^=(d&VSW)

    const int bh = blockIdx.x;
    const int b = bh / NH_, h = bh % NH_;
    const int qtile = blockIdx.y;
    const int tid = threadIdx.x, ln = tid & 63, wv = tid >> 6;
    const int ln15 = ln & 15, lhi = ln >> 4;
    const __hip_bfloat16* qkbase = qkb + (size_t)b * Nt * (2 * C_);

    // ---- stage K: linear LDS dest + pre-swizzled global source (m173) ----
#pragma unroll
    for (int it = 0; it < NPAD * 8 / 256; ++it) {
        const int p = it * 256 + tid;
        int key = p >> 3;
        const int c = (p & 7) ^ (key & 7);
        if (key >= Nt) key = Nt - 1;               // clamp (masked later)
        unsigned short* dst = sK + (size_t)(it * 256 + (wv << 6)) * 8;   // wave-uniform
        gload16(dst, qkbase + (size_t)key * (2 * C_) + C_ + h * HD_ + (c << 3));
    }
    // ---- stage V^T (zero padded keys!) ----
    const unsigned short* vsrc = (const unsigned short*)vbuf;
#pragma unroll
    for (int it = 0; it < NPAD * 64 / 256; ++it) {
        const int e = it * 256 + tid;
        const int d = e & 63, key = e >> 6;
        unsigned short val = 0;
        if (key < Nt) val = vsrc[((size_t)b * Nt + key) * C_ + h * HD_ + d];
        *(unsigned short*)((char*)sV + d * ROWB + ((((key >> 3) ^ (d & VSW))) << 4) + ((key & 7) << 1)) = val;
    }
    // ---- Q fragments from global ----
    const int qbase = qtile * 64 + (wv << 4);
    int qrow = qbase + ln15; if (qrow >= Nt) qrow = Nt - 1;
    const __hip_bfloat16* qp = qkbase + (size_t)qrow * (2 * C_) + h * HD_ + (lhi << 3);
    const bf16x8 qf0 = *(const bf16x8*)qp;
    const bf16x8 qf1 = *(const bf16x8*)(qp + 32);
    __syncthreads();

    // ---- S^T = K @ Q^T : lane -> (query=ln15, keys=t*16+lhi*4+r) ----
    f32x4 sc[NT16];
#pragma unroll
    for (int t = 0; t < NT16; ++t) {
        const int key = (t << 4) + ln15;
        const unsigned short* kr = sK + (size_t)key * 64;
        const bf16x8 k0 = *(const bf16x8*)(kr + ((lhi ^ (key & 7)) << 3));
        const bf16x8 k1 = *(const bf16x8*)(kr + (((4 + lhi) ^ (key & 7)) << 3));
        f32x4 a = {0.f, 0.f, 0.f, 0.f};
        a = __builtin_amdgcn_mfma_f32_16x16x32_bf16(k0, qf0, a, 0, 0, 0);
        a = __builtin_amdgcn_mfma_f32_16x16x32_bf16(k1, qf1, a, 0, 0, 0);
        sc[t] = a;
    }
    __syncthreads();   // all waves done reading K before P overwrites it

    // ---- softmax over keys (mask >= Nt), row split across lhi groups ----
    float mx = -1e30f;
#pragma unroll
    for (int t = 0; t < NT16; ++t)
#pragma unroll
        for (int r = 0; r < 4; ++r) {
            const int key = (t << 4) + (lhi << 2) + r;
            const float v = (key < Nt) ? sc[t][r] * 0.125f : -1e30f;
            sc[t][r] = v;
            mx = fmaxf(mx, v);
        }
    mx = fmaxf(mx, __shfl_xor(mx, 16));
    mx = fmaxf(mx, __shfl_xor(mx, 32));
    float sum = 0.f;
#pragma unroll
    for (int t = 0; t < NT16; ++t)
#pragma unroll
        for (int r = 0; r < 4; ++r) {
            const float e = expf(sc[t][r] - mx);
            sc[t][r] = e; sum += e;
        }
    sum += __shfl_xor(sum, 16);
    sum += __shfl_xor(sum, 32);
    const float inv = 1.f / sum;

    // ---- write P (bf16) into per-wave region of sK; packed 4 keys = 8B ----
    unsigned short* Pw = sK + wv * (16 * NPAD);
    const bool isQ0 = (qtile == 0) && (wv == 0) && (ln15 == 0);
#pragma unroll
    for (int t = 0; t < NT16; ++t) {
        union { unsigned short us[4]; uint2 u2; } pk;
#pragma unroll
        for (int r = 0; r < 4; ++r) {
            const float p = sc[t][r] * inv;
            const __hip_bfloat16 hb = __float2bfloat16(p);
            pk.us[r] = *(const unsigned short*)&hb;
            if (isQ0) {
                const int key = (t << 4) + (lhi << 2) + r;
                if (key < Nt) attn0[(size_t)bh * NTOK + key] = p;
            }
        }
        const int chunk = ((t << 1) + (lhi >> 1)) ^ (ln15 & VSW);
        *(uint2*)((char*)Pw + ln15 * ROWB + (chunk << 4) + ((lhi & 1) << 3)) = pk.u2;
    }
    __syncthreads();

    // ---- O = P @ V : acc (q = lhi*4+r, d = n*16+ln15) ----
    f32x4 oa[4] = {};
#pragma unroll
    for (int s = 0; s < NPAD / 32; ++s) {
        const bf16x8 pf = *(const bf16x8*)((char*)Pw + ln15 * ROWB +
                                           (((((s << 2) + lhi)) ^ (ln15 & VSW)) << 4));
#pragma unroll
        for (int n = 0; n < 4; ++n) {
            const int d = (n << 4) + ln15;
            const bf16x8 vf = *(const bf16x8*)((char*)sV + d * ROWB +
                                               (((((s << 2) + lhi)) ^ (d & VSW)) << 4));
            oa[n] = __builtin_amdgcn_mfma_f32_16x16x32_bf16(pf, vf, oa[n], 0, 0, 0);
        }
    }
#pragma unroll
    for (int n = 0; n < 4; ++n)
#pragma unroll
        for (int r = 0; r < 4; ++r) {
            const int qq = qbase + (lhi << 2) + r;
            if (qq < Nt)
                o[((size_t)b * Nt + qq) * C_ + h * HD_ + (n << 4) + ln15] =
                    __float2bfloat16(oa[n][r]);
        }
}

// ---------------- cls-attention row ----------------
__global__ __launch_bounds__(256) void row_kernel(const float* __restrict__ attn0,
                                                  float* __restrict__ row, int Nt)
{
    const int b = blockIdx.x, m = threadIdx.x;
    if (m < Nt - 1) {
        float s = 0.f;
#pragma unroll
        for (int h = 0; h < NH_; ++h) s += attn0[((size_t)(b * NH_ + h)) * NTOK + 1 + m];
        row[b * NP_ + m] = s;
    }
}

__global__ __launch_bounds__(256) void cls_ema_kernel(float* cls, const float* __restrict__ row, int first)
{
    const int i = blockIdx.x * 256 + threadIdx.x;
    if (i < B_ * NP_) cls[i] = first ? row[i] : 0.5f * cls[i] + 0.5f * row[i];
}

// ---------------- stable descending rank-sort ----------------
__global__ __launch_bounds__(256) void rank_kernel(const float* __restrict__ cls,
                                                   int* __restrict__ idx,
                                                   float* __restrict__ sorted,
                                                   float* __restrict__ ssum)
{
    __shared__ float sv[NP_];
    const int b = blockIdx.x, t = threadIdx.x;
    if (t < NP_) sv[t] = cls[b * NP_ + t];
    __syncthreads();
    float val = 0.f; int r = NP_;
    if (t < NP_) {
        val = sv[t];
        r = 0;
        for (int j = 0; j < NP_; ++j) {
            const float vj = sv[j];
            r += (vj > val || (vj == val && j < t)) ? 1 : 0;
        }
        idx[b * NP_ + r] = t;
        sorted[b * NP_ + r] = val;
    }
    const float contrib = (t < NP_ && r >= NKEEP) ? val : 0.f;
    const float tot = blockReduceSum256(contrib);
    if (t == 0) ssum[b] = tot;
}

// ---------------- build xs / fast / rep ----------------
__global__ __launch_bounds__(256) void build_xs_kernel(const float* __restrict__ x,
                                                       const int* __restrict__ idx,
                                                       const float* __restrict__ sorted,
                                                       const float* __restrict__ ssum,
                                                       float* __restrict__ xs,
                                                       float* __restrict__ fast,
                                                       float* __restrict__ rep)
{
    const int b = blockIdx.x, t = blockIdx.y, tid = threadIdx.x;
    const float* xb = x + (size_t)b * NTOK * C_;
    if (t == 0) {
#pragma unroll
        for (int j = 0; j < 3; ++j) {
            const int c = tid + j * 256;
            xs[(size_t)b * 100 * C_ + c] = xb[c];
        }
    } else if (t <= NKEEP) {
        const int src = 1 + idx[b * NP_ + (t - 1)];
#pragma unroll
        for (int j = 0; j < 3; ++j) {
            const int c = tid + j * 256;
            xs[((size_t)b * 100 + t) * C_ + c] = xb[(size_t)src * C_ + c];
        }
    } else if (t == NKEEP + 1) {
        const float inv = 1.f / ssum[b];
        float acc0 = 0.f, acc1 = 0.f, acc2 = 0.f;
        for (int jj = 0; jj < NP_ - NKEEP; ++jj) {
            const int src = 1 + idx[b * NP_ + NKEEP + jj];
            const float wgt = sorted[b * NP_ + NKEEP + jj];
            const float* xr = xb + (size_t)src * C_;
            acc0 = fmaf(xr[tid], wgt, acc0);
            acc1 = fmaf(xr[tid + 256], wgt, acc1);
            acc2 = fmaf(xr[tid + 512], wgt, acc2);
        }
        float* xsr = xs + ((size_t)b * 100 + 99) * C_;
        float* rr = rep + (size_t)b * C_;
        xsr[tid] = acc0 * inv;       rr[tid] = acc0 * inv;
        xsr[tid + 256] = acc1 * inv; rr[tid + 256] = acc1 * inv;
        xsr[tid + 512] = acc2 * inv; rr[tid + 512] = acc2 * inv;
    } else {
        const int jf = t - (NKEEP + 2);
        const int src = 1 + idx[b * NP_ + NKEEP + jf];
#pragma unroll
        for (int j = 0; j < 3; ++j) {
            const int c = tid + j * 256;
            fast[((size_t)b * (NP_ - NKEEP) + jf) * C_ + c] = xb[(size_t)src * C_ + c];
        }
    }
}

__global__ __launch_bounds__(256) void scatter_back_kernel(const float* __restrict__ xs,
                                                           const float* __restrict__ fast,
                                                           const float* __restrict__ rep,
                                                           float* __restrict__ x)
{
    const int b = blockIdx.x, t = blockIdx.y, tid = threadIdx.x;
#pragma unroll
    for (int j = 0; j < 3; ++j) {
        const int c = tid + j * 256;
        float v;
        if (t <= NKEEP)
            v = xs[((size_t)b * 100 + t) * C_ + c];
        else
            v = fast[((size_t)b * (NP_ - NKEEP) + (t - NKEEP - 1)) * C_ + c]
                + 0.5f * (xs[((size_t)b * 100 + 99) * C_ + c] - rep[(size_t)b * C_ + c]);
        x[((size_t)b * NTOK + t) * C_ + c] = v;
    }
}

__global__ __launch_bounds__(256) void cls_prune_update_kernel(float* cls,
                                                               const float* __restrict__ sorted,
                                                               const float* __restrict__ row)
{
    const int i = blockIdx.x * 256 + threadIdx.x;
    if (i < B_ * NP_) {
        const int m = i % NP_;
        const float sv = sorted[i];
        cls[i] = (m < NKEEP) ? 0.5f * sv + 0.5f * row[(i / NP_) * NP_ + m] : sv;
    }
}

// ---------------- host ----------------
extern "C" void kernel_launch(void* const* d_in, const int* in_sizes, int n_in,
                              void* d_out, int out_size, void* d_ws, size_t ws_size,
                              hipStream_t stream)
{
    (void)in_sizes; (void)n_in; (void)out_size;
    const float* x_img   = (const float*)d_in[0];
    const float* cls_tok = (const float*)d_in[1];
    const float* pos     = (const float*)d_in[2];
    const float* patch_w = (const float*)d_in[3];
    const float* patch_b = (const float*)d_in[4];
    const float* ln1_g   = (const float*)d_in[5];
    const float* ln1_b   = (const float*)d_in[6];
    const float* qk_w    = (const float*)d_in[7];
    const float* qk_b    = (const float*)d_in[8];
    const float* v_w     = (const float*)d_in[9];
    const float* v_b     = (const float*)d_in[10];
    const float* proj_w  = (const float*)d_in[11];
    const float* proj_b  = (const float*)d_in[12];
    const float* ln2_g   = (const float*)d_in[13];
    const float* ln2_b   = (const float*)d_in[14];
    const float* fc1_w   = (const float*)d_in[15];
    const float* fc1_b   = (const float*)d_in[16];
    const float* fc2_w   = (const float*)d_in[17];
    const float* fc2_b   = (const float*)d_in[18];
    const float* norm_g  = (const float*)d_in[19];
    const float* norm_b  = (const float*)d_in[20];
    const float* head_w  = (const float*)d_in[21];
    const float* head_b  = (const float*)d_in[22];

    char* base = (char*)d_ws;
    size_t off = 0;
    auto alloc = [&](size_t bytes) -> void* {
        void* p = base + off; off = (off + bytes + 255) & ~(size_t)255; return p;
    };
    float* X    = (float*)alloc((size_t)MPAD * C_ * 4);
    __hip_bfloat16* Tb  = (__hip_bfloat16*)alloc((size_t)MPAD * C_ * 2);
    __hip_bfloat16* QKb = (__hip_bfloat16*)alloc((size_t)MPAD * 2 * C_ * 2);
    __hip_bfloat16* Vb  = (__hip_bfloat16*)alloc((size_t)MPAD * C_ * 2);
    __hip_bfloat16* Hb  = (__hip_bfloat16*)alloc((size_t)MPAD * 4 * C_ * 2);
    float* XS   = (float*)alloc((size_t)3200 * C_ * 4);
    float* FAST = (float*)alloc((size_t)B_ * (NP_ - NKEEP) * C_ * 4);
    float* REP  = (float*)alloc((size_t)B_ * C_ * 4);
    float* ATTN0= (float*)alloc((size_t)B_ * NH_ * NTOK * 4);
    float* ROW  = (float*)alloc((size_t)B_ * NP_ * 4);
    float* CLS  = (float*)alloc((size_t)B_ * NP_ * 4);
    float* SORT = (float*)alloc((size_t)B_ * NP_ * 4);
    float* SSUM = (float*)alloc((size_t)B_ * 4);
    float* T0   = (float*)alloc((size_t)B_ * C_ * 4);
    int*   IDX  = (int*)alloc((size_t)B_ * NP_ * 4);
    __hip_bfloat16* WTpatch = (__hip_bfloat16*)alloc((size_t)C_ * C_ * 2);
    __hip_bfloat16* WTqk    = (__hip_bfloat16*)alloc((size_t)12 * C_ * 2 * C_ * 2);
    __hip_bfloat16* WTv     = (__hip_bfloat16*)alloc((size_t)12 * C_ * C_ * 2);
    __hip_bfloat16* WTproj  = (__hip_bfloat16*)alloc((size_t)12 * C_ * C_ * 2);
    __hip_bfloat16* WTfc1   = (__hip_bfloat16*)alloc((size_t)12 * C_ * 4 * C_ * 2);
    __hip_bfloat16* WTfc2   = (__hip_bfloat16*)alloc((size_t)12 * 4 * C_ * C_ * 2);
    if (off > ws_size) return;

    __hip_bfloat16* Ob    = Hb;   // attn output aliases Hb
    __hip_bfloat16* PATCH = Hb;
    float*          PEMB  = (float*)QKb;  // patch-phase alias (fp32 pemb fits in QKb)

    const dim3 blk(256);

    transpose_bf16_kernel<<<dim3(C_ / 32, C_ / 32, 1), blk, 0, stream>>>(patch_w, WTpatch, C_, C_);
    transpose_bf16_kernel<<<dim3(2 * C_ / 32, C_ / 32, 12), blk, 0, stream>>>(qk_w, WTqk, C_, 2 * C_);
    transpose_bf16_kernel<<<dim3(C_ / 32, C_ / 32, 12), blk, 0, stream>>>(v_w, WTv, C_, C_);
    transpose_bf16_kernel<<<dim3(C_ / 32, C_ / 32, 12), blk, 0, stream>>>(proj_w, WTproj, C_, C_);
    transpose_bf16_kernel<<<dim3(4 * C_ / 32, C_ / 32, 12), blk, 0, stream>>>(fc1_w, WTfc1, C_, 4 * C_);
    transpose_bf16_kernel<<<dim3(C_ / 32, 4 * C_ / 32, 12), blk, 0, stream>>>(fc2_w, WTfc2, 4 * C_, C_);

    auto runBlock = [&](int i, float* xb, int Nt) {
        const int M = B_ * Nt;
        const int mt = (M + 127) >> 7;
        const int qtiles = (Nt + 63) >> 6;
        ln_kernel<<<M, blk, 0, stream>>>(xb, ln1_g + i * C_, ln1_b + i * C_, Tb, nullptr, C_);
        gemm_bf16_kernel<<<dim3(12, mt), blk, 0, stream>>>(
            Tb, WTqk + (size_t)i * 2 * C_ * C_, qk_b + (size_t)i * 2 * C_, nullptr, nullptr, QKb, C_, 2 * C_, 0);
        gemm_bf16_kernel<<<dim3(6, mt), blk, 0, stream>>>(
            Tb, WTv + (size_t)i * C_ * C_, v_b + (size_t)i * C_, nullptr, nullptr, Vb, C_, C_, 0);
        if (Nt == NTOK)
            attn_mfma_kernel<14><<<dim3(B_ * NH_, qtiles), blk, 0, stream>>>(QKb, Vb, Ob, ATTN0, Nt);
        else
            attn_mfma_kernel<8><<<dim3(B_ * NH_, qtiles), blk, 0, stream>>>(QKb, Vb, Ob, ATTN0, Nt);
        row_kernel<<<B_, blk, 0, stream>>>(ATTN0, ROW, Nt);
        gemm_bf16_kernel<<<dim3(6, mt), blk, 0, stream>>>(
            Ob, WTproj + (size_t)i * C_ * C_, proj_b + (size_t)i * C_, xb, xb, nullptr, C_, C_, 0);
        ln_kernel<<<M, blk, 0, stream>>>(xb, ln2_g + i * C_, ln2_b + i * C_, Tb, nullptr, C_);
        gemm_bf16_kernel<<<dim3(24, mt), blk, 0, stream>>>(
            Tb, WTfc1 + (size_t)i * C_ * 4 * C_, fc1_b + (size_t)i * 4 * C_, nullptr, nullptr, Hb, C_, 4 * C_, 1);
        gemm_bf16_kernel<<<dim3(6, mt), blk, 0, stream>>>(
            Hb, WTfc2 + (size_t)i * 4 * C_ * C_, fc2_b + (size_t)i * C_, xb, xb, nullptr, 4 * C_, C_, 0);
    };

    // ---- patch embedding ----
    patchify_kernel<<<B_ * NP_, blk, 0, stream>>>(x_img, PATCH);
    gemm_bf16_kernel<<<dim3(6, 49), blk, 0, stream>>>(
        PATCH, WTpatch, patch_b, nullptr, PEMB, nullptr, C_, C_, 0);
    assemble_x_kernel<<<dim3(B_, NTOK), blk, 0, stream>>>(PEMB, cls_tok, pos, X);

    // ---- 12 transformer blocks ----
    for (int i = 0; i < 12; ++i) {
        if (i < 4) {
            runBlock(i, X, NTOK);
            cls_ema_kernel<<<(B_ * NP_ + 255) / 256, blk, 0, stream>>>(CLS, ROW, i == 0 ? 1 : 0);
        } else {
            rank_kernel<<<B_, blk, 0, stream>>>(CLS, IDX, SORT, SSUM);
            build_xs_kernel<<<dim3(B_, 198), blk, 0, stream>>>(X, IDX, SORT, SSUM, XS, FAST, REP);
            runBlock(i, XS, 100);
            scatter_back_kernel<<<dim3(B_, NTOK), blk, 0, stream>>>(XS, FAST, REP, X);
            cls_prune_update_kernel<<<(B_ * NP_ + 255) / 256, blk, 0, stream>>>(CLS, SORT, ROW);
        }
    }

    // ---- final LN (token 0 only) + head ----
    ln_kernel<<<B_, blk, 0, stream>>>(X, norm_g, norm_b, nullptr, T0, (long long)NTOK * C_);
    gemm_f32_kernel<<<dim3((NCLS_ + 127) / 128, 1), blk, 0, stream>>>(
        T0, head_w, head_b, nullptr, (float*)d_out, B_, NCLS_, C_, 0);
}

// Round 4
// 3770.396 us; speedup vs baseline: 5.8359x; 1.1568x over previous
//
#include <hip/hip_runtime.h>
#include <hip/hip_bf16.h>
#include <stdint.h>

#define B_ 32
#define C_ 768
#define NH_ 12
#define HD_ 64
#define NP_ 196
#define NTOK 197
#define NKEEP 98
#define NCLS_ 1000
#define MPAD 6400
#define RS_ (3 * C_)   // QKV row stride

typedef __bf16 bf16x8 __attribute__((ext_vector_type(8)));
typedef float f32x4 __attribute__((ext_vector_type(4)));

// ---------------- block reduction (256 threads) ----------------
__device__ __forceinline__ float blockReduceSum256(float v) {
    __shared__ float red[4];
    const int lane = threadIdx.x & 63, w = threadIdx.x >> 6;
#pragma unroll
    for (int off = 32; off; off >>= 1) v += __shfl_down(v, off);
    __syncthreads();
    if (lane == 0) red[w] = v;
    __syncthreads();
    return red[0] + red[1] + red[2] + red[3];
}

// ---------------- async global->LDS (16B per lane) ----------------
__device__ __forceinline__ void gload16(void* lds, const void* g) {
    __builtin_amdgcn_global_load_lds(
        (const __attribute__((address_space(1))) void*)g,
        (__attribute__((address_space(3))) void*)lds,
        16, 0, 0);
}

// ---------------- patchify: (B,3,224,224) -> bf16 (B*196, 768) ----------------
__global__ __launch_bounds__(256) void patchify_kernel(const float* __restrict__ img,
                                                       __hip_bfloat16* __restrict__ patches)
{
    const int bp = blockIdx.x;
    const int b = bp / NP_, p = bp % NP_;
    const int gy = p / 14, gx = p % 14;
    const int tid = threadIdx.x;
#pragma unroll
    for (int j = 0; j < 3; ++j) {
        const int e = tid + j * 256;
        const int c = e >> 8, rem = e & 255, py = rem >> 4, px = rem & 15;
        patches[(size_t)bp * C_ + e] = __float2bfloat16(
            img[(((size_t)b * 3 + c) * 224 + gy * 16 + py) * 224 + gx * 16 + px]);
    }
}

// ---------------- x = concat(cls, pemb) + pos ----------------
__global__ __launch_bounds__(256) void assemble_x_kernel(const float* __restrict__ pemb,
                                                         const float* __restrict__ cls_tok,
                                                         const float* __restrict__ pos,
                                                         float* __restrict__ x)
{
    const int b = blockIdx.x, t = blockIdx.y, tid = threadIdx.x;
#pragma unroll
    for (int j = 0; j < 3; ++j) {
        const int c = tid + j * 256;
        const float v = (t == 0) ? cls_tok[c] : pemb[((size_t)b * NP_ + (t - 1)) * C_ + c];
        x[((size_t)b * NTOK + t) * C_ + c] = v + pos[(size_t)t * C_ + c];
    }
}

// ---------------- layernorm over C=768; bf16 and/or fp32 outputs ----------------
__global__ __launch_bounds__(256) void ln_kernel(const float* __restrict__ x,
                                                 const float* __restrict__ g,
                                                 const float* __restrict__ b,
                                                 __hip_bfloat16* outB, float* outF,
                                                 long long inRowStride)
{
    const int tok = blockIdx.x, tid = threadIdx.x;
    const float* xr = x + (size_t)tok * inRowStride;
    const float v0 = xr[tid], v1 = xr[tid + 256], v2 = xr[tid + 512];
    const float mu = blockReduceSum256(v0 + v1 + v2) * (1.f / C_);
    const float d0 = v0 - mu, d1 = v1 - mu, d2 = v2 - mu;
    const float var = blockReduceSum256(d0 * d0 + d1 * d1 + d2 * d2) * (1.f / C_);
    const float rs = rsqrtf(var + 1e-6f);
    const float o0 = d0 * rs * g[tid]       + b[tid];
    const float o1 = d1 * rs * g[tid + 256] + b[tid + 256];
    const float o2 = d2 * rs * g[tid + 512] + b[tid + 512];
    if (outB) {
        __hip_bfloat16* orow = outB + (size_t)tok * C_;
        orow[tid]       = __float2bfloat16(o0);
        orow[tid + 256] = __float2bfloat16(o1);
        orow[tid + 512] = __float2bfloat16(o2);
    }
    if (outF) {
        float* orow = outF + (size_t)tok * C_;
        orow[tid] = o0; orow[tid + 256] = o1; orow[tid + 512] = o2;
    }
}

// ---------------- weight transpose+convert: fp32 [K][N] -> bf16 [N][K] ----------------
__global__ __launch_bounds__(256) void transpose_bf16_kernel(const float* __restrict__ W,
                                                             __hip_bfloat16* __restrict__ Wt,
                                                             int K, int N,
                                                             long long outLstride, long long outOff)
{
    __shared__ float tile[32][33];
    const size_t loffIn = (size_t)blockIdx.z * K * N;
    const size_t loffOut = (size_t)blockIdx.z * outLstride + outOff;
    const int k0 = blockIdx.y << 5, n0 = blockIdx.x << 5;
    const int tid = threadIdx.x;
#pragma unroll
    for (int e = tid; e < 1024; e += 256) {
        const int r = e >> 5, c = e & 31;
        tile[r][c] = W[loffIn + (size_t)(k0 + r) * N + n0 + c];
    }
    __syncthreads();
#pragma unroll
    for (int e = tid; e < 1024; e += 256) {
        const int r = e >> 5, c = e & 31;
        Wt[loffOut + (size_t)(n0 + r) * K + k0 + c] = __float2bfloat16(tile[c][r]);
    }
}

// ---------------- concat qk_b / v_b into per-layer 2304 bias ----------------
__global__ __launch_bounds__(256) void concat_bias_kernel(const float* __restrict__ qk_b,
                                                          const float* __restrict__ v_b,
                                                          float* __restrict__ out)
{
    const int i = blockIdx.x * 256 + threadIdx.x;
    if (i < 12 * RS_) {
        const int l = i / RS_, c = i % RS_;
        out[i] = (c < 2 * C_) ? qk_b[l * 2 * C_ + c] : v_b[l * C_ + (c - 2 * C_)];
    }
}

// ---------------- bf16 MFMA GEMM (m97 structure) ----------------
__global__ __launch_bounds__(256) void gemm_bf16_kernel(const __hip_bfloat16* __restrict__ A,
                                                        const __hip_bfloat16* __restrict__ Bt,
                                                        const float* __restrict__ bias,
                                                        const float* __restrict__ res,
                                                        float* outF, __hip_bfloat16* outB,
                                                        int K, int N, int act)
{
    __shared__ unsigned short sA[128 * 32];
    __shared__ unsigned short sB[128 * 32];
    const int tid = threadIdx.x;
    const int wv = tid >> 6, ln = tid & 63;
    const int bm = blockIdx.y << 7, bn = blockIdx.x << 7;
    const int wr = wv >> 1, wc = wv & 1;
    const int ln15 = ln & 15, lhi = ln >> 4;

    const int srow = (wv << 4) + (ln >> 2);
    const int scol = (ln & 3) << 3;
    const __hip_bfloat16* gA = A + (size_t)(bm + srow) * K + scol;
    const __hip_bfloat16* gB = Bt + (size_t)(bn + srow) * K + scol;
    unsigned short* lA = sA + (wv << 9);
    unsigned short* lB = sB + (wv << 9);

    f32x4 acc[4][4] = {};
    for (int k0 = 0; k0 < K; k0 += 32) {
        gload16(lA,        gA + k0);
        gload16(lA + 2048, gA + (size_t)64 * K + k0);
        gload16(lB,        gB + k0);
        gload16(lB + 2048, gB + (size_t)64 * K + k0);
        __syncthreads();
        bf16x8 a[4], b[4];
        const bf16x8* SA = (const bf16x8*)sA;
        const bf16x8* SB = (const bf16x8*)sB;
#pragma unroll
        for (int m = 0; m < 4; ++m) a[m] = SA[(((wr << 6) + (m << 4) + ln15) << 2) + lhi];
#pragma unroll
        for (int n = 0; n < 4; ++n) b[n] = SB[(((wc << 6) + (n << 4) + ln15) << 2) + lhi];
#pragma unroll
        for (int m = 0; m < 4; ++m)
#pragma unroll
            for (int n = 0; n < 4; ++n)
                acc[m][n] = __builtin_amdgcn_mfma_f32_16x16x32_bf16(a[m], b[n], acc[m][n], 0, 0, 0);
        __syncthreads();
    }
#pragma unroll
    for (int n = 0; n < 4; ++n) {
        const int gc = bn + (wc << 6) + (n << 4) + ln15;
        const float bv = bias ? bias[gc] : 0.f;
#pragma unroll
        for (int m = 0; m < 4; ++m) {
            const int gr0 = bm + (wr << 6) + (m << 4) + (lhi << 2);
            f32x4 v = acc[m][n];
#pragma unroll
            for (int r = 0; r < 4; ++r) {
                const size_t o = (size_t)(gr0 + r) * N + gc;
                float x = v[r] + bv;
                if (act == 1) x = 0.5f * x * (1.f + erff(x * 0.70710678118654752f));
                if (res) x += res[o];
                if (outF) outF[o] = x;
                if (outB) outB[o] = __float2bfloat16(x);
            }
        }
    }
}

// ---------------- head: out[m][n] = A[m] . W[:,n] + bias (fp32 exact) ----------------
__global__ __launch_bounds__(256) void head_kernel(const float* __restrict__ A,
                                                   const float* __restrict__ W,
                                                   const float* __restrict__ bias,
                                                   float* __restrict__ out)
{
    const int n = blockIdx.x * 256 + threadIdx.x;
    const int m = blockIdx.y;
    if (n >= NCLS_) return;
    const float* a = A + (size_t)m * C_;
    float s = 0.f;
#pragma unroll 8
    for (int k = 0; k < C_; ++k) s = fmaf(a[k], W[(size_t)k * NCLS_ + n], s);
    out[(size_t)m * NCLS_ + n] = s + bias[n];
}

// ---------------- MFMA attention (QKV fused input, row stride 3C) ----------------
// Block = (b*NH+h, qtile). 4 waves x 16 queries. K linear-LDS via gload16 with
// pre-swizzled source; V^T staged vectorized with d>>3-keyed chunk XOR + padded
// rows (bank-spread writes); swapped QK^T; P packed into K region; PV mfma.
template<int NT16>
__global__ __launch_bounds__(256) void attn_mfma_kernel(const __hip_bfloat16* __restrict__ qkv,
                                                        __hip_bfloat16* __restrict__ o,
                                                        float* __restrict__ attn0,
                                                        int Nt)
{
    constexpr int NPAD = NT16 * 16;
    constexpr int PSW = (((NPAD / 8) & 7) == 0) ? 7 : 3;   // P chunk XOR key (ln15)
    constexpr int VSW = 7;                                  // V chunk XOR key (d>>3)
    constexpr int PROWB = NPAD * 2 + 16;                    // P row bytes (padded)
    constexpr int VROWB = (NPAD == 224) ? 528 : 272;        // V^T row bytes (chunk space for XOR)
    __shared__ unsigned short sK[NPAD * 64 + 512];          // K [key][64] linear; P region after S
    __shared__ unsigned short sV[32 * VROWB];               // V^T [d][key], padded+swizzled

    const int bh = blockIdx.x;
    const int b = bh / NH_, h = bh % NH_;
    const int qtile = blockIdx.y;
    const int tid = threadIdx.x, ln = tid & 63, wv = tid >> 6;
    const int ln15 = ln & 15, lhi = ln >> 4;
    const __hip_bfloat16* qkbase = qkv + (size_t)b * Nt * RS_;

    // ---- stage K: linear LDS dest + pre-swizzled global source ----
#pragma unroll
    for (int it = 0; it < NPAD * 8 / 256; ++it) {
        const int p = it * 256 + tid;
        int key = p >> 3;
        const int c = (p & 7) ^ (key & 7);
        if (key >= Nt) key = Nt - 1;               // clamp (masked later)
        unsigned short* dst = sK + (size_t)(it * 256 + (wv << 6)) * 8;   // wave-uniform
        gload16(dst, qkbase + (size_t)key * RS_ + C_ + (h << 6) + (c << 3));
    }
    // ---- stage V^T: 16B vector loads, scatter to padded/swizzled rows ----
#pragma unroll
    for (int it = 0; it < NPAD * 8 / 256; ++it) {
        const int e = it * 256 + tid;
        const int key = e >> 3, dc = e & 7;        // 8 d-elems per chunk
        union { uint4 u; unsigned short us[8]; } val;
        val.u = make_uint4(0u, 0u, 0u, 0u);
        if (key < Nt)
            val.u = *(const uint4*)(qkbase + (size_t)key * RS_ + 2 * C_ + (h << 6) + (dc << 3));
        const int kc = key >> 3, kb = (key & 7) << 1;
#pragma unroll
        for (int j = 0; j < 8; ++j) {
            const int d = (dc << 3) + j;
            *(unsigned short*)((char*)sV + d * VROWB + ((kc ^ ((d >> 3) & VSW)) << 4) + kb) = val.us[j];
        }
    }
    // ---- Q fragments from global ----
    const int qbase = qtile * 64 + (wv << 4);
    int qrow = qbase + ln15; if (qrow >= Nt) qrow = Nt - 1;
    const __hip_bfloat16* qp = qkbase + (size_t)qrow * RS_ + (h << 6) + (lhi << 3);
    const bf16x8 qf0 = *(const bf16x8*)qp;
    const bf16x8 qf1 = *(const bf16x8*)(qp + 32);
    __syncthreads();

    // ---- S^T = K @ Q^T : lane -> (query=ln15, keys=t*16+lhi*4+r) ----
    f32x4 sc[NT16];
#pragma unroll
    for (int t = 0; t < NT16; ++t) {
        const int key = (t << 4) + ln15;
        const unsigned short* kr = sK + (size_t)key * 64;
        const bf16x8 k0 = *(const bf16x8*)(kr + ((lhi ^ (key & 7)) << 3));
        const bf16x8 k1 = *(const bf16x8*)(kr + (((4 + lhi) ^ (key & 7)) << 3));
        f32x4 a = {0.f, 0.f, 0.f, 0.f};
        a = __builtin_amdgcn_mfma_f32_16x16x32_bf16(k0, qf0, a, 0, 0, 0);
        a = __builtin_amdgcn_mfma_f32_16x16x32_bf16(k1, qf1, a, 0, 0, 0);
        sc[t] = a;
    }
    __syncthreads();   // all waves done reading K before P overwrites it

    // ---- softmax over keys (mask >= Nt) ----
    float mx = -1e30f;
#pragma unroll
    for (int t = 0; t < NT16; ++t)
#pragma unroll
        for (int r = 0; r < 4; ++r) {
            const int key = (t << 4) + (lhi << 2) + r;
            const float v = (key < Nt) ? sc[t][r] * 0.125f : -1e30f;
            sc[t][r] = v;
            mx = fmaxf(mx, v);
        }
    mx = fmaxf(mx, __shfl_xor(mx, 16));
    mx = fmaxf(mx, __shfl_xor(mx, 32));
    float sum = 0.f;
#pragma unroll
    for (int t = 0; t < NT16; ++t)
#pragma unroll
        for (int r = 0; r < 4; ++r) {
            const float e = expf(sc[t][r] - mx);
            sc[t][r] = e; sum += e;
        }
    sum += __shfl_xor(sum, 16);
    sum += __shfl_xor(sum, 32);
    const float inv = 1.f / sum;

    // ---- write P (bf16) into per-wave region of sK; packed 4 keys = 8B ----
    char* Pw = (char*)sK + wv * (16 * PROWB);
    const bool isQ0 = (qtile == 0) && (wv == 0) && (ln15 == 0);
#pragma unroll
    for (int t = 0; t < NT16; ++t) {
        union { unsigned short us[4]; uint2 u2; } pk;
#pragma unroll
        for (int r = 0; r < 4; ++r) {
            const float p = sc[t][r] * inv;
            const __hip_bfloat16 hb = __float2bfloat16(p);
            pk.us[r] = *(const unsigned short*)&hb;
            if (isQ0) {
                const int key = (t << 4) + (lhi << 2) + r;
                if (key < Nt) attn0[(size_t)bh * NTOK + key] = p;
            }
        }
        const int chunk = ((t << 1) + (lhi >> 1)) ^ (ln15 & PSW);
        *(uint2*)(Pw + ln15 * PROWB + (chunk << 4) + ((lhi & 1) << 3)) = pk.u2;
    }
    __syncthreads();

    // ---- O = P @ V : acc (q = lhi*4+r, d = n*16+ln15) ----
    f32x4 oa[4] = {};
#pragma unroll
    for (int s = 0; s < NPAD / 32; ++s) {
        const bf16x8 pf = *(const bf16x8*)(Pw + ln15 * PROWB +
                                           ((((s << 2) + lhi) ^ (ln15 & PSW)) << 4));
#pragma unroll
        for (int n = 0; n < 4; ++n) {
            const int d = (n << 4) + ln15;
            const bf16x8 vf = *(const bf16x8*)((char*)sV + d * VROWB +
                                               ((((s << 2) + lhi) ^ ((d >> 3) & VSW)) << 4));
            oa[n] = __builtin_amdgcn_mfma_f32_16x16x32_bf16(pf, vf, oa[n], 0, 0, 0);
        }
    }
#pragma unroll
    for (int n = 0; n < 4; ++n)
#pragma unroll
        for (int r = 0; r < 4; ++r) {
            const int qq = qbase + (lhi << 2) + r;
            if (qq < Nt)
                o[((size_t)b * Nt + qq) * C_ + (h << 6) + (n << 4) + ln15] =
                    __float2bfloat16(oa[n][r]);
        }
}

// ---------------- row + cls EMA (full layers) ----------------
__global__ __launch_bounds__(256) void row_cls_ema_kernel(const float* __restrict__ attn0,
                                                          float* __restrict__ cls, int first)
{
    const int b = blockIdx.x, t = threadIdx.x;
    if (t < NP_) {
        float s = 0.f;
#pragma unroll
        for (int h = 0; h < NH_; ++h) s += attn0[((size_t)(b * NH_ + h)) * NTOK + 1 + t];
        const int i = b * NP_ + t;
        cls[i] = first ? s : 0.5f * cls[i] + 0.5f * s;
    }
}

// ---------------- row + cls update (pruned layers) ----------------
__global__ __launch_bounds__(256) void row_cls_prune_kernel(const float* __restrict__ attn0,
                                                            const float* __restrict__ sorted,
                                                            float* __restrict__ cls)
{
    const int b = blockIdx.x, t = threadIdx.x;
    if (t < NP_) {
        float sv = sorted[b * NP_ + t];
        if (t < NKEEP) {
            float s = 0.f;
#pragma unroll
            for (int h = 0; h < NH_; ++h) s += attn0[((size_t)(b * NH_ + h)) * NTOK + 1 + t];
            sv = 0.5f * sv + 0.5f * s;
        }
        cls[b * NP_ + t] = sv;
    }
}

// ---------------- stable descending rank-sort ----------------
__global__ __launch_bounds__(256) void rank_kernel(const float* __restrict__ cls,
                                                   int* __restrict__ idx,
                                                   float* __restrict__ sorted,
                                                   float* __restrict__ ssum)
{
    __shared__ float sv[NP_];
    const int b = blockIdx.x, t = threadIdx.x;
    if (t < NP_) sv[t] = cls[b * NP_ + t];
    __syncthreads();
    float val = 0.f; int r = NP_;
    if (t < NP_) {
        val = sv[t];
        r = 0;
        for (int j = 0; j < NP_; ++j) {
            const float vj = sv[j];
            r += (vj > val || (vj == val && j < t)) ? 1 : 0;
        }
        idx[b * NP_ + r] = t;
        sorted[b * NP_ + r] = val;
    }
    const float contrib = (t < NP_ && r >= NKEEP) ? val : 0.f;
    const float tot = blockReduceSum256(contrib);
    if (t == 0) ssum[b] = tot;
}

// ---------------- build xs / fast / rep ----------------
__global__ __launch_bounds__(256) void build_xs_kernel(const float* __restrict__ x,
                                                       const int* __restrict__ idx,
                                                       const float* __restrict__ sorted,
                                                       const float* __restrict__ ssum,
                                                       float* __restrict__ xs,
                                                       float* __restrict__ fast,
                                                       float* __restrict__ rep)
{
    const int b = blockIdx.x, t = blockIdx.y, tid = threadIdx.x;
    const float* xb = x + (size_t)b * NTOK * C_;
    if (t == 0) {
#pragma unroll
        for (int j = 0; j < 3; ++j) {
            const int c = tid + j * 256;
            xs[(size_t)b * 100 * C_ + c] = xb[c];
        }
    } else if (t <= NKEEP) {
        const int src = 1 + idx[b * NP_ + (t - 1)];
#pragma unroll
        for (int j = 0; j < 3; ++j) {
            const int c = tid + j * 256;
            xs[((size_t)b * 100 + t) * C_ + c] = xb[(size_t)src * C_ + c];
        }
    } else if (t == NKEEP + 1) {
        const float inv = 1.f / ssum[b];
        float acc0 = 0.f, acc1 = 0.f, acc2 = 0.f;
        for (int jj = 0; jj < NP_ - NKEEP; ++jj) {
            const int src = 1 + idx[b * NP_ + NKEEP + jj];
            const float wgt = sorted[b * NP_ + NKEEP + jj];
            const float* xr = xb + (size_t)src * C_;
            acc0 = fmaf(xr[tid], wgt, acc0);
            acc1 = fmaf(xr[tid + 256], wgt, acc1);
            acc2 = fmaf(xr[tid + 512], wgt, acc2);
        }
        float* xsr = xs + ((size_t)b * 100 + 99) * C_;
        float* rr = rep + (size_t)b * C_;
        xsr[tid] = acc0 * inv;       rr[tid] = acc0 * inv;
        xsr[tid + 256] = acc1 * inv; rr[tid + 256] = acc1 * inv;
        xsr[tid + 512] = acc2 * inv; rr[tid + 512] = acc2 * inv;
    } else {
        const int jf = t - (NKEEP + 2);
        const int src = 1 + idx[b * NP_ + NKEEP + jf];
#pragma unroll
        for (int j = 0; j < 3; ++j) {
            const int c = tid + j * 256;
            fast[((size_t)b * (NP_ - NKEEP) + jf) * C_ + c] = xb[(size_t)src * C_ + c];
        }
    }
}

__global__ __launch_bounds__(256) void scatter_back_kernel(const float* __restrict__ xs,
                                                           const float* __restrict__ fast,
                                                           const float* __restrict__ rep,
                                                           float* __restrict__ x)
{
    const int b = blockIdx.x, t = blockIdx.y, tid = threadIdx.x;
#pragma unroll
    for (int j = 0; j < 3; ++j) {
        const int c = tid + j * 256;
        float v;
        if (t <= NKEEP)
            v = xs[((size_t)b * 100 + t) * C_ + c];
        else
            v = fast[((size_t)b * (NP_ - NKEEP) + (t - NKEEP - 1)) * C_ + c]
                + 0.5f * (xs[((size_t)b * 100 + 99) * C_ + c] - rep[(size_t)b * C_ + c]);
        x[((size_t)b * NTOK + t) * C_ + c] = v;
    }
}

// ---------------- host ----------------
extern "C" void kernel_launch(void* const* d_in, const int* in_sizes, int n_in,
                              void* d_out, int out_size, void* d_ws, size_t ws_size,
                              hipStream_t stream)
{
    (void)in_sizes; (void)n_in; (void)out_size;
    const float* x_img   = (const float*)d_in[0];
    const float* cls_tok = (const float*)d_in[1];
    const float* pos     = (const float*)d_in[2];
    const float* patch_w = (const float*)d_in[3];
    const float* patch_b = (const float*)d_in[4];
    const float* ln1_g   = (const float*)d_in[5];
    const float* ln1_b   = (const float*)d_in[6];
    const float* qk_w    = (const float*)d_in[7];
    const float* qk_b    = (const float*)d_in[8];
    const float* v_w     = (const float*)d_in[9];
    const float* v_b     = (const float*)d_in[10];
    const float* proj_w  = (const float*)d_in[11];
    const float* proj_b  = (const float*)d_in[12];
    const float* ln2_g   = (const float*)d_in[13];
    const float* ln2_b   = (const float*)d_in[14];
    const float* fc1_w   = (const float*)d_in[15];
    const float* fc1_b   = (const float*)d_in[16];
    const float* fc2_w   = (const float*)d_in[17];
    const float* fc2_b   = (const float*)d_in[18];
    const float* norm_g  = (const float*)d_in[19];
    const float* norm_b  = (const float*)d_in[20];
    const float* head_w  = (const float*)d_in[21];
    const float* head_b  = (const float*)d_in[22];

    char* base = (char*)d_ws;
    size_t off = 0;
    auto alloc = [&](size_t bytes) -> void* {
        void* p = base + off; off = (off + bytes + 255) & ~(size_t)255; return p;
    };
    float* X    = (float*)alloc((size_t)MPAD * C_ * 4);
    __hip_bfloat16* Tb   = (__hip_bfloat16*)alloc((size_t)MPAD * C_ * 2);
    __hip_bfloat16* QKVb = (__hip_bfloat16*)alloc((size_t)MPAD * RS_ * 2);
    __hip_bfloat16* Hb   = (__hip_bfloat16*)alloc((size_t)MPAD * 4 * C_ * 2);
    float* XS   = (float*)alloc((size_t)3200 * C_ * 4);
    float* FAST = (float*)alloc((size_t)B_ * (NP_ - NKEEP) * C_ * 4);
    float* REP  = (float*)alloc((size_t)B_ * C_ * 4);
    float* ATTN0= (float*)alloc((size_t)B_ * NH_ * NTOK * 4);
    float* CLS  = (float*)alloc((size_t)B_ * NP_ * 4);
    float* SORT = (float*)alloc((size_t)B_ * NP_ * 4);
    float* SSUM = (float*)alloc((size_t)B_ * 4);
    float* T0   = (float*)alloc((size_t)B_ * C_ * 4);
    int*   IDX  = (int*)alloc((size_t)B_ * NP_ * 4);
    float* BIASQKV = (float*)alloc((size_t)12 * RS_ * 4);
    __hip_bfloat16* WTpatch = (__hip_bfloat16*)alloc((size_t)C_ * C_ * 2);
    __hip_bfloat16* WTqkv   = (__hip_bfloat16*)alloc((size_t)12 * RS_ * C_ * 2);
    __hip_bfloat16* WTproj  = (__hip_bfloat16*)alloc((size_t)12 * C_ * C_ * 2);
    __hip_bfloat16* WTfc1   = (__hip_bfloat16*)alloc((size_t)12 * C_ * 4 * C_ * 2);
    __hip_bfloat16* WTfc2   = (__hip_bfloat16*)alloc((size_t)12 * 4 * C_ * C_ * 2);
    if (off > ws_size) return;

    __hip_bfloat16* Ob    = Hb;          // attn output aliases Hb
    __hip_bfloat16* PATCH = Hb;
    float*          PEMB  = (float*)QKVb;

    const dim3 blk(256);

    // ---- weight transposes (fp32 [K][N] -> bf16 [N][K]) ----
    transpose_bf16_kernel<<<dim3(24, 24, 1), blk, 0, stream>>>(patch_w, WTpatch, C_, C_, (long long)C_ * C_, 0);
    transpose_bf16_kernel<<<dim3(48, 24, 12), blk, 0, stream>>>(qk_w, WTqkv, C_, 2 * C_, (long long)RS_ * C_, 0);
    transpose_bf16_kernel<<<dim3(24, 24, 12), blk, 0, stream>>>(v_w, WTqkv, C_, C_, (long long)RS_ * C_, (long long)2 * C_ * C_);
    transpose_bf16_kernel<<<dim3(24, 24, 12), blk, 0, stream>>>(proj_w, WTproj, C_, C_, (long long)C_ * C_, 0);
    transpose_bf16_kernel<<<dim3(96, 24, 12), blk, 0, stream>>>(fc1_w, WTfc1, C_, 4 * C_, (long long)4 * C_ * C_, 0);
    transpose_bf16_kernel<<<dim3(24, 96, 12), blk, 0, stream>>>(fc2_w, WTfc2, 4 * C_, C_, (long long)4 * C_ * C_, 0);
    concat_bias_kernel<<<(12 * RS_ + 255) / 256, blk, 0, stream>>>(qk_b, v_b, BIASQKV);

    auto runBlock = [&](int i, float* xb, int Nt) {
        const int M = B_ * Nt;
        const int mt = (M + 127) >> 7;
        const int qtiles = (Nt + 63) >> 6;
        ln_kernel<<<M, blk, 0, stream>>>(xb, ln1_g + i * C_, ln1_b + i * C_, Tb, nullptr, C_);
        gemm_bf16_kernel<<<dim3(RS_ / 128, mt), blk, 0, stream>>>(
            Tb, WTqkv + (size_t)i * RS_ * C_, BIASQKV + (size_t)i * RS_, nullptr, nullptr, QKVb, C_, RS_, 0);
        if (Nt == NTOK)
            attn_mfma_kernel<14><<<dim3(B_ * NH_, qtiles), blk, 0, stream>>>(QKVb, Ob, ATTN0, Nt);
        else
            attn_mfma_kernel<8><<<dim3(B_ * NH_, qtiles), blk, 0, stream>>>(QKVb, Ob, ATTN0, Nt);
        gemm_bf16_kernel<<<dim3(6, mt), blk, 0, stream>>>(
            Ob, WTproj + (size_t)i * C_ * C_, proj_b + (size_t)i * C_, xb, xb, nullptr, C_, C_, 0);
        ln_kernel<<<M, blk, 0, stream>>>(xb, ln2_g + i * C_, ln2_b + i * C_, Tb, nullptr, C_);
        gemm_bf16_kernel<<<dim3(24, mt), blk, 0, stream>>>(
            Tb, WTfc1 + (size_t)i * C_ * 4 * C_, fc1_b + (size_t)i * 4 * C_, nullptr, nullptr, Hb, C_, 4 * C_, 1);
        gemm_bf16_kernel<<<dim3(6, mt), blk, 0, stream>>>(
            Hb, WTfc2 + (size_t)i * 4 * C_ * C_, fc2_b + (size_t)i * C_, xb, xb, nullptr, 4 * C_, C_, 0);
    };

    // ---- patch embedding ----
    patchify_kernel<<<B_ * NP_, blk, 0, stream>>>(x_img, PATCH);
    gemm_bf16_kernel<<<dim3(6, 49), blk, 0, stream>>>(
        PATCH, WTpatch, patch_b, nullptr, PEMB, nullptr, C_, C_, 0);
    assemble_x_kernel<<<dim3(B_, NTOK), blk, 0, stream>>>(PEMB, cls_tok, pos, X);

    // ---- 12 transformer blocks ----
    for (int i = 0; i < 12; ++i) {
        if (i < 4) {
            runBlock(i, X, NTOK);
            row_cls_ema_kernel<<<B_, blk, 0, stream>>>(ATTN0, CLS, i == 0 ? 1 : 0);
        } else {
            rank_kernel<<<B_, blk, 0, stream>>>(CLS, IDX, SORT, SSUM);
            build_xs_kernel<<<dim3(B_, 198), blk, 0, stream>>>(X, IDX, SORT, SSUM, XS, FAST, REP);
            runBlock(i, XS, 100);
            scatter_back_kernel<<<dim3(B_, NTOK), blk, 0, stream>>>(XS, FAST, REP, X);
            row_cls_prune_kernel<<<B_, blk, 0, stream>>>(ATTN0, SORT, CLS);
        }
    }

    // ---- final LN (token 0 only) + head (fp32 exact) ----
    ln_kernel<<<B_, blk, 0, stream>>>(X, norm_g, norm_b, nullptr, T0, (long long)NTOK * C_);
    head_kernel<<<dim3(4, B_), blk, 0, stream>>>(T0, head_w, head_b, (float*)d_out);
}

// Round 5
// 2796.657 us; speedup vs baseline: 7.8679x; 1.3482x over previous
//
#include <hip/hip_runtime.h>
#include <hip/hip_bf16.h>
#include <stdint.h>

#define B_ 32
#define C_ 768
#define NH_ 12
#define HD_ 64
#define NP_ 196
#define NTOK 197
#define NKEEP 98
#define NCLS_ 1000
#define MPAD 6400
#define RS_ (3 * C_)   // QKV row stride

typedef __bf16 bf16x8 __attribute__((ext_vector_type(8)));
typedef float f32x4 __attribute__((ext_vector_type(4)));

// ---------------- block reduction (256 threads) ----------------
__device__ __forceinline__ float blockReduceSum256(float v) {
    __shared__ float red[4];
    const int lane = threadIdx.x & 63, w = threadIdx.x >> 6;
#pragma unroll
    for (int off = 32; off; off >>= 1) v += __shfl_down(v, off);
    __syncthreads();
    if (lane == 0) red[w] = v;
    __syncthreads();
    return red[0] + red[1] + red[2] + red[3];
}

// ---------------- async global->LDS (16B per lane) ----------------
__device__ __forceinline__ void gload16(void* lds, const void* g) {
    __builtin_amdgcn_global_load_lds(
        (const __attribute__((address_space(1))) void*)g,
        (__attribute__((address_space(3))) void*)lds,
        16, 0, 0);
}

// ---------------- patchify: (B,3,224,224) -> bf16 (B*196, 768) ----------------
__global__ __launch_bounds__(256) void patchify_kernel(const float* __restrict__ img,
                                                       __hip_bfloat16* __restrict__ patches)
{
    const int bp = blockIdx.x;
    const int b = bp / NP_, p = bp % NP_;
    const int gy = p / 14, gx = p % 14;
    const int tid = threadIdx.x;
#pragma unroll
    for (int j = 0; j < 3; ++j) {
        const int e = tid + j * 256;
        const int c = e >> 8, rem = e & 255, py = rem >> 4, px = rem & 15;
        patches[(size_t)bp * C_ + e] = __float2bfloat16(
            img[(((size_t)b * 3 + c) * 224 + gy * 16 + py) * 224 + gx * 16 + px]);
    }
}

// ---------------- x = concat(cls, pemb) + pos ----------------
__global__ __launch_bounds__(256) void assemble_x_kernel(const float* __restrict__ pemb,
                                                         const float* __restrict__ cls_tok,
                                                         const float* __restrict__ pos,
                                                         float* __restrict__ x)
{
    const int b = blockIdx.x, t = blockIdx.y, tid = threadIdx.x;
#pragma unroll
    for (int j = 0; j < 3; ++j) {
        const int c = tid + j * 256;
        const float v = (t == 0) ? cls_tok[c] : pemb[((size_t)b * NP_ + (t - 1)) * C_ + c];
        x[((size_t)b * NTOK + t) * C_ + c] = v + pos[(size_t)t * C_ + c];
    }
}

// ---------------- layernorm: wave per row, no block barriers ----------------
__global__ __launch_bounds__(256) void ln_kernel(const float* __restrict__ x,
                                                 const float* __restrict__ g,
                                                 const float* __restrict__ b,
                                                 __hip_bfloat16* outB, float* outF,
                                                 long long inRowStride, int nRows)
{
    const int row = (blockIdx.x << 2) + (threadIdx.x >> 6);
    const int lane = threadIdx.x & 63;
    if (row >= nRows) return;
    const float* xr = x + (size_t)row * inRowStride;
    float4 v0 = *(const float4*)(xr + (lane << 2));
    float4 v1 = *(const float4*)(xr + 256 + (lane << 2));
    float4 v2 = *(const float4*)(xr + 512 + (lane << 2));
    float s = v0.x + v0.y + v0.z + v0.w + v1.x + v1.y + v1.z + v1.w
            + v2.x + v2.y + v2.z + v2.w;
#pragma unroll
    for (int off = 1; off < 64; off <<= 1) s += __shfl_xor(s, off);
    const float mu = s * (1.f / C_);
    float q = 0.f;
    {
        float d;
        d = v0.x - mu; q += d * d; d = v0.y - mu; q += d * d;
        d = v0.z - mu; q += d * d; d = v0.w - mu; q += d * d;
        d = v1.x - mu; q += d * d; d = v1.y - mu; q += d * d;
        d = v1.z - mu; q += d * d; d = v1.w - mu; q += d * d;
        d = v2.x - mu; q += d * d; d = v2.y - mu; q += d * d;
        d = v2.z - mu; q += d * d; d = v2.w - mu; q += d * d;
    }
#pragma unroll
    for (int off = 1; off < 64; off <<= 1) q += __shfl_xor(q, off);
    const float rs = rsqrtf(q * (1.f / C_) + 1e-6f);
    const float4 vv[3] = {v0, v1, v2};
#pragma unroll
    for (int j = 0; j < 3; ++j) {
        const int cbase = (j << 8) + (lane << 2);
        const float4 gv = *(const float4*)(g + cbase);
        const float4 bv = *(const float4*)(b + cbase);
        float o0 = (vv[j].x - mu) * rs * gv.x + bv.x;
        float o1 = (vv[j].y - mu) * rs * gv.y + bv.y;
        float o2 = (vv[j].z - mu) * rs * gv.z + bv.z;
        float o3 = (vv[j].w - mu) * rs * gv.w + bv.w;
        if (outB) {
            union { unsigned short us[4]; uint2 u; } pk;
            __hip_bfloat16 h;
            h = __float2bfloat16(o0); pk.us[0] = *(unsigned short*)&h;
            h = __float2bfloat16(o1); pk.us[1] = *(unsigned short*)&h;
            h = __float2bfloat16(o2); pk.us[2] = *(unsigned short*)&h;
            h = __float2bfloat16(o3); pk.us[3] = *(unsigned short*)&h;
            *(uint2*)((unsigned short*)outB + (size_t)row * C_ + cbase) = pk.u;
        }
        if (outF) {
            float4 o; o.x = o0; o.y = o1; o.z = o2; o.w = o3;
            *(float4*)(outF + (size_t)row * C_ + cbase) = o;
        }
    }
}

// ---------------- weight transpose+convert: fp32 [K][N] -> bf16 [N][K] ----------------
__global__ __launch_bounds__(256) void transpose_bf16_kernel(const float* __restrict__ W,
                                                             __hip_bfloat16* __restrict__ Wt,
                                                             int K, int N,
                                                             long long outLstride, long long outOff)
{
    __shared__ float tile[32][33];
    const size_t loffIn = (size_t)blockIdx.z * K * N;
    const size_t loffOut = (size_t)blockIdx.z * outLstride + outOff;
    const int k0 = blockIdx.y << 5, n0 = blockIdx.x << 5;
    const int tid = threadIdx.x;
#pragma unroll
    for (int e = tid; e < 1024; e += 256) {
        const int r = e >> 5, c = e & 31;
        tile[r][c] = W[loffIn + (size_t)(k0 + r) * N + n0 + c];
    }
    __syncthreads();
#pragma unroll
    for (int e = tid; e < 1024; e += 256) {
        const int r = e >> 5, c = e & 31;
        Wt[loffOut + (size_t)(n0 + r) * K + k0 + c] = __float2bfloat16(tile[c][r]);
    }
}

// ---------------- concat qk_b / v_b into per-layer 2304 bias ----------------
__global__ __launch_bounds__(256) void concat_bias_kernel(const float* __restrict__ qk_b,
                                                          const float* __restrict__ v_b,
                                                          float* __restrict__ out)
{
    const int i = blockIdx.x * 256 + threadIdx.x;
    if (i < 12 * RS_) {
        const int l = i / RS_, c = i % RS_;
        out[i] = (c < 2 * C_) ? qk_b[l * 2 * C_ + c] : v_b[l * C_ + (c - 2 * C_)];
    }
}

// ---------------- bf16 MFMA GEMM: 128x128 tile, BK=64, XCD swizzle ----------------
// Staging: linear LDS dest + pre-swizzled global source (chunk ^= row&7);
// frag ds_reads XOR the same key -> conflict-free. OMODE 0: bf16 out via LDS
// repack + dwordx4 stores; 1: f32 out + residual; 2: f32 out.
template<int GELU, int OMODE>
__global__ __launch_bounds__(256) void gemm_bf16_kernel(const __hip_bfloat16* __restrict__ A,
                                                        const __hip_bfloat16* __restrict__ Bt,
                                                        const float* __restrict__ bias,
                                                        const float* __restrict__ res,
                                                        float* __restrict__ outF,
                                                        __hip_bfloat16* __restrict__ outB,
                                                        int K, int N)
{
    __shared__ __align__(16) unsigned short sAB[2][128 * 64];
    unsigned short* sA = sAB[0];
    unsigned short* sB = sAB[1];
    const int tid = threadIdx.x;
    const int wv = tid >> 6, ln = tid & 63;

    // bijective XCD swizzle (m204)
    const int nwg = gridDim.x * gridDim.y;
    int lid = blockIdx.y * gridDim.x + blockIdx.x;
    {
        const int q = nwg >> 3, r = nwg & 7;
        const int xcd = lid & 7, lq = lid >> 3;
        lid = (xcd < r ? xcd * (q + 1) : r * (q + 1) + (xcd - r) * q) + lq;
    }
    const int bn = (lid % gridDim.x) << 7;
    const int bm = (lid / gridDim.x) << 7;

    const int wr = wv >> 1, wc = wv & 1;
    const int ln15 = ln & 15, lhi = ln >> 4;

    // staging: thread t -> row t>>3, physical chunk t&7, global chunk swizzled
    const int srow = tid >> 3;
    const int gc = (tid & 7) ^ ((tid >> 3) & 7);
    const __hip_bfloat16* gA = A + (size_t)(bm + srow) * K + (gc << 3);
    const __hip_bfloat16* gB = Bt + (size_t)(bn + srow) * K + (gc << 3);
    unsigned short* lA = sA + (wv << 9);
    unsigned short* lB = sB + (wv << 9);

    f32x4 acc[4][4] = {};
    const int swk = ln15 & 7;          // frag row & 7
    for (int k0 = 0; k0 < K; k0 += 64) {
#pragma unroll
        for (int i = 0; i < 4; ++i) {
            gload16(lA + (i << 11), gA + (size_t)(i << 5) * K + k0);
            gload16(lB + (i << 11), gB + (size_t)(i << 5) * K + k0);
        }
        __syncthreads();
#pragma unroll
        for (int kk = 0; kk < 2; ++kk) {
            const int ch = ((kk << 2) + lhi) ^ swk;
            bf16x8 a[4], b[4];
#pragma unroll
            for (int m = 0; m < 4; ++m)
                a[m] = *(const bf16x8*)(sA + (((wr << 6) + (m << 4) + ln15) << 6) + (ch << 3));
#pragma unroll
            for (int n = 0; n < 4; ++n)
                b[n] = *(const bf16x8*)(sB + (((wc << 6) + (n << 4) + ln15) << 6) + (ch << 3));
#pragma unroll
            for (int m = 0; m < 4; ++m)
#pragma unroll
                for (int n = 0; n < 4; ++n)
                    acc[m][n] = __builtin_amdgcn_mfma_f32_16x16x32_bf16(a[m], b[n], acc[m][n], 0, 0, 0);
        }
        __syncthreads();
    }

    if (OMODE == 0) {
        // bf16 repack through LDS (reuse staging: 128x128 ushorts = 32KB)
        unsigned short* sOut = sAB[0];
#pragma unroll
        for (int n = 0; n < 4; ++n) {
            const int col = (wc << 6) + (n << 4) + ln15;
            const float bv = bias[bn + col];
#pragma unroll
            for (int m = 0; m < 4; ++m) {
                const int row0 = (wr << 6) + (m << 4) + (lhi << 2);
#pragma unroll
                for (int r = 0; r < 4; ++r) {
                    float x = acc[m][n][r] + bv;
                    if (GELU) x = 0.5f * x * (1.f + erff(x * 0.70710678118654752f));
                    const __hip_bfloat16 hb = __float2bfloat16(x);
                    sOut[(row0 + r) * 128 + col] = *(const unsigned short*)&hb;
                }
            }
        }
        __syncthreads();
#pragma unroll
        for (int i = 0; i < 8; ++i) {
            const int chunk = (i << 8) + tid;
            const int row = chunk >> 4, c8 = (chunk & 15) << 3;
            *(uint4*)((unsigned short*)outB + (size_t)(bm + row) * N + bn + c8) =
                *(const uint4*)(sOut + row * 128 + c8);
        }
    } else {
#pragma unroll
        for (int n = 0; n < 4; ++n) {
            const int gcn = bn + (wc << 6) + (n << 4) + ln15;
            const float bv = bias[gcn];
#pragma unroll
            for (int m = 0; m < 4; ++m) {
                const int gr0 = bm + (wr << 6) + (m << 4) + (lhi << 2);
                f32x4 v = acc[m][n];
#pragma unroll
                for (int r = 0; r < 4; ++r) {
                    const size_t o = (size_t)(gr0 + r) * N + gcn;
                    float x = v[r] + bv;
                    if (OMODE == 1) x += res[o];
                    outF[o] = x;
                }
            }
        }
    }
}

// ---------------- head: out[m][n] = A[m] . W[:,n] + bias (fp32 exact) ----------------
__global__ __launch_bounds__(256) void head_kernel(const float* __restrict__ A,
                                                   const float* __restrict__ W,
                                                   const float* __restrict__ bias,
                                                   float* __restrict__ out)
{
    const int n = blockIdx.x * 256 + threadIdx.x;
    const int m = blockIdx.y;
    if (n >= NCLS_) return;
    const float* a = A + (size_t)m * C_;
    float s = 0.f;
#pragma unroll 8
    for (int k = 0; k < C_; ++k) s = fmaf(a[k], W[(size_t)k * NCLS_ + n], s);
    out[(size_t)m * NCLS_ + n] = s + bias[n];
}

// ---------------- MFMA attention (QKV fused input, row stride 3C) ----------------
template<int NT16>
__global__ __launch_bounds__(256) void attn_mfma_kernel(const __hip_bfloat16* __restrict__ qkv,
                                                        __hip_bfloat16* __restrict__ o,
                                                        float* __restrict__ attn0,
                                                        int Nt)
{
    constexpr int NPAD = NT16 * 16;
    constexpr int PSW = (((NPAD / 8) & 7) == 0) ? 7 : 3;   // P chunk XOR key (ln15)
    constexpr int VSW = 7;                                  // V chunk XOR key (d>>3)
    constexpr int PROWB = NPAD * 2 + 16;                    // P row bytes (padded)
    constexpr int VROWB = (NPAD == 224) ? 528 : 272;        // V^T row bytes
    __shared__ unsigned short sK[NPAD * 64 + 512];          // K [key][64] linear; P after S
    __shared__ unsigned short sV[32 * VROWB];               // V^T [d][key] (bytes = 64*VROWB)

    const int bh = blockIdx.x;
    const int b = bh / NH_, h = bh % NH_;
    const int qtile = blockIdx.y;
    const int tid = threadIdx.x, ln = tid & 63, wv = tid >> 6;
    const int ln15 = ln & 15, lhi = ln >> 4;
    const __hip_bfloat16* qkbase = qkv + (size_t)b * Nt * RS_;

    // ---- stage K: linear LDS dest + pre-swizzled global source ----
#pragma unroll
    for (int it = 0; it < NPAD * 8 / 256; ++it) {
        const int p = it * 256 + tid;
        int key = p >> 3;
        const int c = (p & 7) ^ (key & 7);
        if (key >= Nt) key = Nt - 1;               // clamp (masked later)
        unsigned short* dst = sK + (size_t)(it * 256 + (wv << 6)) * 8;   // wave-uniform
        gload16(dst, qkbase + (size_t)key * RS_ + C_ + (h << 6) + (c << 3));
    }
    // ---- stage V^T: 16B vector loads, scatter to padded/swizzled rows ----
#pragma unroll
    for (int it = 0; it < NPAD * 8 / 256; ++it) {
        const int e = it * 256 + tid;
        const int key = e >> 3, dc = e & 7;        // 8 d-elems per chunk
        union { uint4 u; unsigned short us[8]; } val;
        val.u = make_uint4(0u, 0u, 0u, 0u);
        if (key < Nt)
            val.u = *(const uint4*)(qkbase + (size_t)key * RS_ + 2 * C_ + (h << 6) + (dc << 3));
        const int kc = key >> 3, kb = (key & 7) << 1;
#pragma unroll
        for (int j = 0; j < 8; ++j) {
            const int d = (dc << 3) + j;
            *(unsigned short*)((char*)sV + d * VROWB + ((kc ^ ((d >> 3) & VSW)) << 4) + kb) = val.us[j];
        }
    }
    // ---- Q fragments from global ----
    const int qbase = qtile * 64 + (wv << 4);
    int qrow = qbase + ln15; if (qrow >= Nt) qrow = Nt - 1;
    const __hip_bfloat16* qp = qkbase + (size_t)qrow * RS_ + (h << 6) + (lhi << 3);
    const bf16x8 qf0 = *(const bf16x8*)qp;
    const bf16x8 qf1 = *(const bf16x8*)(qp + 32);
    __syncthreads();

    // ---- S^T = K @ Q^T ----
    f32x4 sc[NT16];
#pragma unroll
    for (int t = 0; t < NT16; ++t) {
        const int key = (t << 4) + ln15;
        const unsigned short* kr = sK + (size_t)key * 64;
        const bf16x8 k0 = *(const bf16x8*)(kr + ((lhi ^ (key & 7)) << 3));
        const bf16x8 k1 = *(const bf16x8*)(kr + (((4 + lhi) ^ (key & 7)) << 3));
        f32x4 a = {0.f, 0.f, 0.f, 0.f};
        a = __builtin_amdgcn_mfma_f32_16x16x32_bf16(k0, qf0, a, 0, 0, 0);
        a = __builtin_amdgcn_mfma_f32_16x16x32_bf16(k1, qf1, a, 0, 0, 0);
        sc[t] = a;
    }
    __syncthreads();   // all waves done reading K before P overwrites it

    // ---- softmax over keys (mask >= Nt) ----
    float mx = -1e30f;
#pragma unroll
    for (int t = 0; t < NT16; ++t)
#pragma unroll
        for (int r = 0; r < 4; ++r) {
            const int key = (t << 4) + (lhi << 2) + r;
            const float v = (key < Nt) ? sc[t][r] * 0.125f : -1e30f;
            sc[t][r] = v;
            mx = fmaxf(mx, v);
        }
    mx = fmaxf(mx, __shfl_xor(mx, 16));
    mx = fmaxf(mx, __shfl_xor(mx, 32));
    float sum = 0.f;
#pragma unroll
    for (int t = 0; t < NT16; ++t)
#pragma unroll
        for (int r = 0; r < 4; ++r) {
            const float e = expf(sc[t][r] - mx);
            sc[t][r] = e; sum += e;
        }
    sum += __shfl_xor(sum, 16);
    sum += __shfl_xor(sum, 32);
    const float inv = 1.f / sum;

    // ---- write P (bf16) into per-wave region of sK ----
    char* Pw = (char*)sK + wv * (16 * PROWB);
    const bool isQ0 = (qtile == 0) && (wv == 0) && (ln15 == 0);
#pragma unroll
    for (int t = 0; t < NT16; ++t) {
        union { unsigned short us[4]; uint2 u2; } pk;
#pragma unroll
        for (int r = 0; r < 4; ++r) {
            const float p = sc[t][r] * inv;
            const __hip_bfloat16 hb = __float2bfloat16(p);
            pk.us[r] = *(const unsigned short*)&hb;
            if (isQ0) {
                const int key = (t << 4) + (lhi << 2) + r;
                if (key < Nt) attn0[(size_t)bh * NTOK + key] = p;
            }
        }
        const int chunk = ((t << 1) + (lhi >> 1)) ^ (ln15 & PSW);
        *(uint2*)(Pw + ln15 * PROWB + (chunk << 4) + ((lhi & 1) << 3)) = pk.u2;
    }
    __syncthreads();

    // ---- O = P @ V ----
    f32x4 oa[4] = {};
#pragma unroll
    for (int s = 0; s < NPAD / 32; ++s) {
        const bf16x8 pf = *(const bf16x8*)(Pw + ln15 * PROWB +
                                           ((((s << 2) + lhi) ^ (ln15 & PSW)) << 4));
#pragma unroll
        for (int n = 0; n < 4; ++n) {
            const int d = (n << 4) + ln15;
            const bf16x8 vf = *(const bf16x8*)((char*)sV + d * VROWB +
                                               ((((s << 2) + lhi) ^ ((d >> 3) & VSW)) << 4));
            oa[n] = __builtin_amdgcn_mfma_f32_16x16x32_bf16(pf, vf, oa[n], 0, 0, 0);
        }
    }
#pragma unroll
    for (int n = 0; n < 4; ++n)
#pragma unroll
        for (int r = 0; r < 4; ++r) {
            const int qq = qbase + (lhi << 2) + r;
            if (qq < Nt)
                o[((size_t)b * Nt + qq) * C_ + (h << 6) + (n << 4) + ln15] =
                    __float2bfloat16(oa[n][r]);
        }
}

// ---------------- row + cls EMA (full layers) ----------------
__global__ __launch_bounds__(256) void row_cls_ema_kernel(const float* __restrict__ attn0,
                                                          float* __restrict__ cls, int first)
{
    const int b = blockIdx.x, t = threadIdx.x;
    if (t < NP_) {
        float s = 0.f;
#pragma unroll
        for (int h = 0; h < NH_; ++h) s += attn0[((size_t)(b * NH_ + h)) * NTOK + 1 + t];
        const int i = b * NP_ + t;
        cls[i] = first ? s : 0.5f * cls[i] + 0.5f * s;
    }
}

// ---------------- row + cls update (pruned layers) ----------------
__global__ __launch_bounds__(256) void row_cls_prune_kernel(const float* __restrict__ attn0,
                                                            const float* __restrict__ sorted,
                                                            float* __restrict__ cls)
{
    const int b = blockIdx.x, t = threadIdx.x;
    if (t < NP_) {
        float sv = sorted[b * NP_ + t];
        if (t < NKEEP) {
            float s = 0.f;
#pragma unroll
            for (int h = 0; h < NH_; ++h) s += attn0[((size_t)(b * NH_ + h)) * NTOK + 1 + t];
            sv = 0.5f * sv + 0.5f * s;
        }
        cls[b * NP_ + t] = sv;
    }
}

// ---------------- stable descending rank-sort ----------------
__global__ __launch_bounds__(256) void rank_kernel(const float* __restrict__ cls,
                                                   int* __restrict__ idx,
                                                   float* __restrict__ sorted,
                                                   float* __restrict__ ssum)
{
    __shared__ float sv[NP_];
    const int b = blockIdx.x, t = threadIdx.x;
    if (t < NP_) sv[t] = cls[b * NP_ + t];
    __syncthreads();
    float val = 0.f; int r = NP_;
    if (t < NP_) {
        val = sv[t];
        r = 0;
        for (int j = 0; j < NP_; ++j) {
            const float vj = sv[j];
            r += (vj > val || (vj == val && j < t)) ? 1 : 0;
        }
        idx[b * NP_ + r] = t;
        sorted[b * NP_ + r] = val;
    }
    const float contrib = (t < NP_ && r >= NKEEP) ? val : 0.f;
    const float tot = blockReduceSum256(contrib);
    if (t == 0) ssum[b] = tot;
}

// ---------------- build xs / fast / rep ----------------
__global__ __launch_bounds__(256) void build_xs_kernel(const float* __restrict__ x,
                                                       const int* __restrict__ idx,
                                                       const float* __restrict__ sorted,
                                                       const float* __restrict__ ssum,
                                                       float* __restrict__ xs,
                                                       float* __restrict__ fast,
                                                       float* __restrict__ rep)
{
    const int b = blockIdx.x, t = blockIdx.y, tid = threadIdx.x;
    const float* xb = x + (size_t)b * NTOK * C_;
    if (t == 0) {
#pragma unroll
        for (int j = 0; j < 3; ++j) {
            const int c = tid + j * 256;
            xs[(size_t)b * 100 * C_ + c] = xb[c];
        }
    } else if (t <= NKEEP) {
        const int src = 1 + idx[b * NP_ + (t - 1)];
#pragma unroll
        for (int j = 0; j < 3; ++j) {
            const int c = tid + j * 256;
            xs[((size_t)b * 100 + t) * C_ + c] = xb[(size_t)src * C_ + c];
        }
    } else if (t == NKEEP + 1) {
        const float inv = 1.f / ssum[b];
        float acc0 = 0.f, acc1 = 0.f, acc2 = 0.f;
        for (int jj = 0; jj < NP_ - NKEEP; ++jj) {
            const int src = 1 + idx[b * NP_ + NKEEP + jj];
            const float wgt = sorted[b * NP_ + NKEEP + jj];
            const float* xr = xb + (size_t)src * C_;
            acc0 = fmaf(xr[tid], wgt, acc0);
            acc1 = fmaf(xr[tid + 256], wgt, acc1);
            acc2 = fmaf(xr[tid + 512], wgt, acc2);
        }
        float* xsr = xs + ((size_t)b * 100 + 99) * C_;
        float* rr = rep + (size_t)b * C_;
        xsr[tid] = acc0 * inv;       rr[tid] = acc0 * inv;
        xsr[tid + 256] = acc1 * inv; rr[tid + 256] = acc1 * inv;
        xsr[tid + 512] = acc2 * inv; rr[tid + 512] = acc2 * inv;
    } else {
        const int jf = t - (NKEEP + 2);
        const int src = 1 + idx[b * NP_ + NKEEP + jf];
#pragma unroll
        for (int j = 0; j < 3; ++j) {
            const int c = tid + j * 256;
            fast[((size_t)b * (NP_ - NKEEP) + jf) * C_ + c] = xb[(size_t)src * C_ + c];
        }
    }
}

__global__ __launch_bounds__(256) void scatter_back_kernel(const float* __restrict__ xs,
                                                           const float* __restrict__ fast,
                                                           const float* __restrict__ rep,
                                                           float* __restrict__ x)
{
    const int b = blockIdx.x, t = blockIdx.y, tid = threadIdx.x;
#pragma unroll
    for (int j = 0; j < 3; ++j) {
        const int c = tid + j * 256;
        float v;
        if (t <= NKEEP)
            v = xs[((size_t)b * 100 + t) * C_ + c];
        else
            v = fast[((size_t)b * (NP_ - NKEEP) + (t - NKEEP - 1)) * C_ + c]
                + 0.5f * (xs[((size_t)b * 100 + 99) * C_ + c] - rep[(size_t)b * C_ + c]);
        x[((size_t)b * NTOK + t) * C_ + c] = v;
    }
}

// ---------------- host ----------------
extern "C" void kernel_launch(void* const* d_in, const int* in_sizes, int n_in,
                              void* d_out, int out_size, void* d_ws, size_t ws_size,
                              hipStream_t stream)
{
    (void)in_sizes; (void)n_in; (void)out_size;
    const float* x_img   = (const float*)d_in[0];
    const float* cls_tok = (const float*)d_in[1];
    const float* pos     = (const float*)d_in[2];
    const float* patch_w = (const float*)d_in[3];
    const float* patch_b = (const float*)d_in[4];
    const float* ln1_g   = (const float*)d_in[5];
    const float* ln1_b   = (const float*)d_in[6];
    const float* qk_w    = (const float*)d_in[7];
    const float* qk_b    = (const float*)d_in[8];
    const float* v_w     = (const float*)d_in[9];
    const float* v_b     = (const float*)d_in[10];
    const float* proj_w  = (const float*)d_in[11];
    const float* proj_b  = (const float*)d_in[12];
    const float* ln2_g   = (const float*)d_in[13];
    const float* ln2_b   = (const float*)d_in[14];
    const float* fc1_w   = (const float*)d_in[15];
    const float* fc1_b   = (const float*)d_in[16];
    const float* fc2_w   = (const float*)d_in[17];
    const float* fc2_b   = (const float*)d_in[18];
    const float* norm_g  = (const float*)d_in[19];
    const float* norm_b  = (const float*)d_in[20];
    const float* head_w  = (const float*)d_in[21];
    const float* head_b  = (const float*)d_in[22];

    char* base = (char*)d_ws;
    size_t off = 0;
    auto alloc = [&](size_t bytes) -> void* {
        void* p = base + off; off = (off + bytes + 255) & ~(size_t)255; return p;
    };
    float* X    = (float*)alloc((size_t)MPAD * C_ * 4);
    __hip_bfloat16* Tb   = (__hip_bfloat16*)alloc((size_t)MPAD * C_ * 2);
    __hip_bfloat16* QKVb = (__hip_bfloat16*)alloc((size_t)MPAD * RS_ * 2);
    __hip_bfloat16* Hb   = (__hip_bfloat16*)alloc((size_t)MPAD * 4 * C_ * 2);
    float* XS   = (float*)alloc((size_t)3200 * C_ * 4);
    float* FAST = (float*)alloc((size_t)B_ * (NP_ - NKEEP) * C_ * 4);
    float* REP  = (float*)alloc((size_t)B_ * C_ * 4);
    float* ATTN0= (float*)alloc((size_t)B_ * NH_ * NTOK * 4);
    float* CLS  = (float*)alloc((size_t)B_ * NP_ * 4);
    float* SORT = (float*)alloc((size_t)B_ * NP_ * 4);
    float* SSUM = (float*)alloc((size_t)B_ * 4);
    float* T0   = (float*)alloc((size_t)B_ * C_ * 4);
    int*   IDX  = (int*)alloc((size_t)B_ * NP_ * 4);
    float* BIASQKV = (float*)alloc((size_t)12 * RS_ * 4);
    __hip_bfloat16* WTpatch = (__hip_bfloat16*)alloc((size_t)C_ * C_ * 2);
    __hip_bfloat16* WTqkv   = (__hip_bfloat16*)alloc((size_t)12 * RS_ * C_ * 2);
    __hip_bfloat16* WTproj  = (__hip_bfloat16*)alloc((size_t)12 * C_ * C_ * 2);
    __hip_bfloat16* WTfc1   = (__hip_bfloat16*)alloc((size_t)12 * C_ * 4 * C_ * 2);
    __hip_bfloat16* WTfc2   = (__hip_bfloat16*)alloc((size_t)12 * 4 * C_ * C_ * 2);
    if (off > ws_size) return;

    __hip_bfloat16* Ob    = Hb;          // attn output aliases Hb
    __hip_bfloat16* PATCH = Hb;
    float*          PEMB  = (float*)QKVb;

    const dim3 blk(256);

    // ---- weight transposes (fp32 [K][N] -> bf16 [N][K]) ----
    transpose_bf16_kernel<<<dim3(24, 24, 1), blk, 0, stream>>>(patch_w, WTpatch, C_, C_, (long long)C_ * C_, 0);
    transpose_bf16_kernel<<<dim3(48, 24, 12), blk, 0, stream>>>(qk_w, WTqkv, C_, 2 * C_, (long long)RS_ * C_, 0);
    transpose_bf16_kernel<<<dim3(24, 24, 12), blk, 0, stream>>>(v_w, WTqkv, C_, C_, (long long)RS_ * C_, (long long)2 * C_ * C_);
    transpose_bf16_kernel<<<dim3(24, 24, 12), blk, 0, stream>>>(proj_w, WTproj, C_, C_, (long long)C_ * C_, 0);
    transpose_bf16_kernel<<<dim3(96, 24, 12), blk, 0, stream>>>(fc1_w, WTfc1, C_, 4 * C_, (long long)4 * C_ * C_, 0);
    transpose_bf16_kernel<<<dim3(24, 96, 12), blk, 0, stream>>>(fc2_w, WTfc2, 4 * C_, C_, (long long)4 * C_ * C_, 0);
    concat_bias_kernel<<<(12 * RS_ + 255) / 256, blk, 0, stream>>>(qk_b, v_b, BIASQKV);

    auto runBlock = [&](int i, float* xb, int Nt) {
        const int M = B_ * Nt;
        const int mt = (M + 127) >> 7;
        const int qtiles = (Nt + 63) >> 6;
        ln_kernel<<<(M + 3) / 4, blk, 0, stream>>>(xb, ln1_g + i * C_, ln1_b + i * C_, Tb, nullptr, C_, M);
        gemm_bf16_kernel<0, 0><<<dim3(RS_ / 128, mt), blk, 0, stream>>>(
            Tb, WTqkv + (size_t)i * RS_ * C_, BIASQKV + (size_t)i * RS_, nullptr, nullptr, QKVb, C_, RS_);
        if (Nt == NTOK)
            attn_mfma_kernel<14><<<dim3(B_ * NH_, qtiles), blk, 0, stream>>>(QKVb, Ob, ATTN0, Nt);
        else
            attn_mfma_kernel<8><<<dim3(B_ * NH_, qtiles), blk, 0, stream>>>(QKVb, Ob, ATTN0, Nt);
        gemm_bf16_kernel<0, 1><<<dim3(6, mt), blk, 0, stream>>>(
            Ob, WTproj + (size_t)i * C_ * C_, proj_b + (size_t)i * C_, xb, xb, nullptr, C_, C_);
        ln_kernel<<<(M + 3) / 4, blk, 0, stream>>>(xb, ln2_g + i * C_, ln2_b + i * C_, Tb, nullptr, C_, M);
        gemm_bf16_kernel<1, 0><<<dim3(24, mt), blk, 0, stream>>>(
            Tb, WTfc1 + (size_t)i * C_ * 4 * C_, fc1_b + (size_t)i * 4 * C_, nullptr, nullptr, Hb, C_, 4 * C_);
        gemm_bf16_kernel<0, 1><<<dim3(6, mt), blk, 0, stream>>>(
            Hb, WTfc2 + (size_t)i * 4 * C_ * C_, fc2_b + (size_t)i * C_, xb, xb, nullptr, 4 * C_, C_);
    };

    // ---- patch embedding ----
    patchify_kernel<<<B_ * NP_, blk, 0, stream>>>(x_img, PATCH);
    gemm_bf16_kernel<0, 2><<<dim3(6, 49), blk, 0, stream>>>(
        PATCH, WTpatch, patch_b, nullptr, PEMB, nullptr, C_, C_);
    assemble_x_kernel<<<dim3(B_, NTOK), blk, 0, stream>>>(PEMB, cls_tok, pos, X);

    // ---- 12 transformer blocks ----
    for (int i = 0; i < 12; ++i) {
        if (i < 4) {
            runBlock(i, X, NTOK);
            row_cls_ema_kernel<<<B_, blk, 0, stream>>>(ATTN0, CLS, i == 0 ? 1 : 0);
        } else {
            rank_kernel<<<B_, blk, 0, stream>>>(CLS, IDX, SORT, SSUM);
            build_xs_kernel<<<dim3(B_, 198), blk, 0, stream>>>(X, IDX, SORT, SSUM, XS, FAST, REP);
            runBlock(i, XS, 100);
            scatter_back_kernel<<<dim3(B_, NTOK), blk, 0, stream>>>(XS, FAST, REP, X);
            row_cls_prune_kernel<<<B_, blk, 0, stream>>>(ATTN0, SORT, CLS);
        }
    }

    // ---- final LN (token 0 only) + head (fp32 exact) ----
    ln_kernel<<<8, blk, 0, stream>>>(X, norm_g, norm_b, nullptr, T0, (long long)NTOK * C_, B_);
    head_kernel<<<dim3(4, B_), blk, 0, stream>>>(T0, head_w, head_b, (float*)d_out);
}

// Round 6
// 2726.822 us; speedup vs baseline: 8.0694x; 1.0256x over previous
//
#include <hip/hip_runtime.h>
#include <hip/hip_bf16.h>
#include <stdint.h>

#define B_ 32
#define C_ 768
#define NH_ 12
#define HD_ 64
#define NP_ 196
#define NTOK 197
#define NKEEP 98
#define NCLS_ 1000
#define MPAD 6400
#define RS_ (3 * C_)   // QKV row stride

typedef __bf16 bf16x8 __attribute__((ext_vector_type(8)));
typedef float f32x4 __attribute__((ext_vector_type(4)));

// ---------------- block reduction (256 threads) ----------------
__device__ __forceinline__ float blockReduceSum256(float v) {
    __shared__ float red[4];
    const int lane = threadIdx.x & 63, w = threadIdx.x >> 6;
#pragma unroll
    for (int off = 32; off; off >>= 1) v += __shfl_down(v, off);
    __syncthreads();
    if (lane == 0) red[w] = v;
    __syncthreads();
    return red[0] + red[1] + red[2] + red[3];
}

// ---------------- async global->LDS (16B per lane) ----------------
__device__ __forceinline__ void gload16(void* lds, const void* g) {
    __builtin_amdgcn_global_load_lds(
        (const __attribute__((address_space(1))) void*)g,
        (__attribute__((address_space(3))) void*)lds,
        16, 0, 0);
}

// ---------------- patchify: (B,3,224,224) -> bf16 (B*196, 768) ----------------
__global__ __launch_bounds__(256) void patchify_kernel(const float* __restrict__ img,
                                                       __hip_bfloat16* __restrict__ patches)
{
    const int bp = blockIdx.x;
    const int b = bp / NP_, p = bp % NP_;
    const int gy = p / 14, gx = p % 14;
    const int tid = threadIdx.x;
#pragma unroll
    for (int j = 0; j < 3; ++j) {
        const int e = tid + j * 256;
        const int c = e >> 8, rem = e & 255, py = rem >> 4, px = rem & 15;
        patches[(size_t)bp * C_ + e] = __float2bfloat16(
            img[(((size_t)b * 3 + c) * 224 + gy * 16 + py) * 224 + gx * 16 + px]);
    }
}

// ---------------- x = concat(cls, pemb) + pos ----------------
__global__ __launch_bounds__(256) void assemble_x_kernel(const float* __restrict__ pemb,
                                                         const float* __restrict__ cls_tok,
                                                         const float* __restrict__ pos,
                                                         float* __restrict__ x)
{
    const int b = blockIdx.x, t = blockIdx.y, tid = threadIdx.x;
#pragma unroll
    for (int j = 0; j < 3; ++j) {
        const int c = tid + j * 256;
        const float v = (t == 0) ? cls_tok[c] : pemb[((size_t)b * NP_ + (t - 1)) * C_ + c];
        x[((size_t)b * NTOK + t) * C_ + c] = v + pos[(size_t)t * C_ + c];
    }
}

// ---------------- layernorm: wave per row, no block barriers ----------------
__global__ __launch_bounds__(256) void ln_kernel(const float* __restrict__ x,
                                                 const float* __restrict__ g,
                                                 const float* __restrict__ b,
                                                 __hip_bfloat16* outB, float* outF,
                                                 long long inRowStride, int nRows)
{
    const int row = (blockIdx.x << 2) + (threadIdx.x >> 6);
    const int lane = threadIdx.x & 63;
    if (row >= nRows) return;
    const float* xr = x + (size_t)row * inRowStride;
    float4 v0 = *(const float4*)(xr + (lane << 2));
    float4 v1 = *(const float4*)(xr + 256 + (lane << 2));
    float4 v2 = *(const float4*)(xr + 512 + (lane << 2));
    float s = v0.x + v0.y + v0.z + v0.w + v1.x + v1.y + v1.z + v1.w
            + v2.x + v2.y + v2.z + v2.w;
#pragma unroll
    for (int off = 1; off < 64; off <<= 1) s += __shfl_xor(s, off);
    const float mu = s * (1.f / C_);
    float q = 0.f;
    {
        float d;
        d = v0.x - mu; q += d * d; d = v0.y - mu; q += d * d;
        d = v0.z - mu; q += d * d; d = v0.w - mu; q += d * d;
        d = v1.x - mu; q += d * d; d = v1.y - mu; q += d * d;
        d = v1.z - mu; q += d * d; d = v1.w - mu; q += d * d;
        d = v2.x - mu; q += d * d; d = v2.y - mu; q += d * d;
        d = v2.z - mu; q += d * d; d = v2.w - mu; q += d * d;
    }
#pragma unroll
    for (int off = 1; off < 64; off <<= 1) q += __shfl_xor(q, off);
    const float rs = rsqrtf(q * (1.f / C_) + 1e-6f);
    const float4 vv[3] = {v0, v1, v2};
#pragma unroll
    for (int j = 0; j < 3; ++j) {
        const int cbase = (j << 8) + (lane << 2);
        const float4 gv = *(const float4*)(g + cbase);
        const float4 bv = *(const float4*)(b + cbase);
        float o0 = (vv[j].x - mu) * rs * gv.x + bv.x;
        float o1 = (vv[j].y - mu) * rs * gv.y + bv.y;
        float o2 = (vv[j].z - mu) * rs * gv.z + bv.z;
        float o3 = (vv[j].w - mu) * rs * gv.w + bv.w;
        if (outB) {
            union { unsigned short us[4]; uint2 u; } pk;
            __hip_bfloat16 h;
            h = __float2bfloat16(o0); pk.us[0] = *(unsigned short*)&h;
            h = __float2bfloat16(o1); pk.us[1] = *(unsigned short*)&h;
            h = __float2bfloat16(o2); pk.us[2] = *(unsigned short*)&h;
            h = __float2bfloat16(o3); pk.us[3] = *(unsigned short*)&h;
            *(uint2*)((unsigned short*)outB + (size_t)row * C_ + cbase) = pk.u;
        }
        if (outF) {
            float4 o; o.x = o0; o.y = o1; o.z = o2; o.w = o3;
            *(float4*)(outF + (size_t)row * C_ + cbase) = o;
        }
    }
}

// ---------------- weight transpose+convert: fp32 [K][N] -> bf16 [N][K] ----------------
__global__ __launch_bounds__(256) void transpose_bf16_kernel(const float* __restrict__ W,
                                                             __hip_bfloat16* __restrict__ Wt,
                                                             int K, int N,
                                                             long long outLstride, long long outOff)
{
    __shared__ float tile[32][33];
    const size_t loffIn = (size_t)blockIdx.z * K * N;
    const size_t loffOut = (size_t)blockIdx.z * outLstride + outOff;
    const int k0 = blockIdx.y << 5, n0 = blockIdx.x << 5;
    const int tid = threadIdx.x;
#pragma unroll
    for (int e = tid; e < 1024; e += 256) {
        const int r = e >> 5, c = e & 31;
        tile[r][c] = W[loffIn + (size_t)(k0 + r) * N + n0 + c];
    }
    __syncthreads();
#pragma unroll
    for (int e = tid; e < 1024; e += 256) {
        const int r = e >> 5, c = e & 31;
        Wt[loffOut + (size_t)(n0 + r) * K + k0 + c] = __float2bfloat16(tile[c][r]);
    }
}

// ---------------- concat qk_b / v_b into per-layer 2304 bias ----------------
__global__ __launch_bounds__(256) void concat_bias_kernel(const float* __restrict__ qk_b,
                                                          const float* __restrict__ v_b,
                                                          float* __restrict__ out)
{
    const int i = blockIdx.x * 256 + threadIdx.x;
    if (i < 12 * RS_) {
        const int l = i / RS_, c = i % RS_;
        out[i] = (c < 2 * C_) ? qk_b[l * 2 * C_ + c] : v_b[l * C_ + (c - 2 * C_)];
    }
}

// ---------------- bf16 MFMA GEMM: 128x128 tile, BK=64, double-buffered ----------------
// T3/T4: stage next K-tile (8 global_load_lds), s_waitcnt vmcnt(8) (prev tile
// landed, next stays in flight), raw s_barrier, inline-asm ds_read_b128 +
// lgkmcnt(0) + sched_barrier(0) (rule #18), MFMA, barrier. XOR chunk swizzle
// both sides (G21). OMODE 0: bf16 out via LDS repack; 1: f32+res; 2: f32.
template<int GELU, int OMODE>
__global__ __launch_bounds__(256) void gemm_bf16_kernel(const __hip_bfloat16* __restrict__ A,
                                                        const __hip_bfloat16* __restrict__ Bt,
                                                        const float* __restrict__ bias,
                                                        const float* __restrict__ res,
                                                        float* __restrict__ outF,
                                                        __hip_bfloat16* __restrict__ outB,
                                                        int K, int N)
{
    __shared__ __align__(16) unsigned short sLDS[4][128 * 64];  // A0,B0,A1,B1 (16KB each)
    const int tid = threadIdx.x;
    const int wv = tid >> 6, ln = tid & 63;

    // bijective XCD swizzle (m204)
    const int nwg = gridDim.x * gridDim.y;
    int lid = blockIdx.y * gridDim.x + blockIdx.x;
    {
        const int q = nwg >> 3, r = nwg & 7;
        const int xcd = lid & 7, lq = lid >> 3;
        lid = (xcd < r ? xcd * (q + 1) : r * (q + 1) + (xcd - r) * q) + lq;
    }
    const int bn = (lid % gridDim.x) << 7;
    const int bm = (lid / gridDim.x) << 7;

    const int wr = wv >> 1, wc = wv & 1;
    const int ln15 = ln & 15, lhi = ln >> 4;

    // staging: thread t -> row t>>3, physical chunk t&7, global chunk swizzled
    const int srow = tid >> 3;
    const int gc = (tid & 7) ^ ((tid >> 3) & 7);
    const __hip_bfloat16* gA = A + (size_t)(bm + srow) * K + (gc << 3);
    const __hip_bfloat16* gB = Bt + (size_t)(bn + srow) * K + (gc << 3);

    const unsigned ldsBase =
        (unsigned)(size_t)(__attribute__((address_space(3))) unsigned short*)&sLDS[0][0];
    unsigned rowA[4], rowB[4];
#pragma unroll
    for (int m = 0; m < 4; ++m) rowA[m] = (unsigned)(((wr << 6) + (m << 4) + ln15) << 7);
#pragma unroll
    for (int n = 0; n < 4; ++n) rowB[n] = (unsigned)(((wc << 6) + (n << 4) + ln15) << 7);
    const int swk = ln15 & 7;

    f32x4 acc[4][4] = {};

    auto stage = [&](int bufA, int bufB, int k0) {
#pragma unroll
        for (int i = 0; i < 4; ++i) {
            gload16(&sLDS[bufA][(wv << 9) + (i << 11)], gA + (size_t)(i << 5) * K + k0);
            gload16(&sLDS[bufB][(wv << 9) + (i << 11)], gB + (size_t)(i << 5) * K + k0);
        }
    };
    auto compute = [&](unsigned aOff, unsigned bOff) {
#pragma unroll
        for (int kk = 0; kk < 2; ++kk) {
            const unsigned chb = (unsigned)(((((kk << 2) + lhi)) ^ swk) << 4);
            bf16x8 a[4], b[4];
#pragma unroll
            for (int m = 0; m < 4; ++m)
                asm volatile("ds_read_b128 %0, %1"
                             : "=v"(a[m]) : "v"(ldsBase + aOff + rowA[m] + chb));
#pragma unroll
            for (int n = 0; n < 4; ++n)
                asm volatile("ds_read_b128 %0, %1"
                             : "=v"(b[n]) : "v"(ldsBase + bOff + rowB[n] + chb));
            asm volatile("s_waitcnt lgkmcnt(0)" ::: "memory");
            __builtin_amdgcn_sched_barrier(0);
#pragma unroll
            for (int m = 0; m < 4; ++m)
#pragma unroll
                for (int n = 0; n < 4; ++n)
                    acc[m][n] = __builtin_amdgcn_mfma_f32_16x16x32_bf16(a[m], b[n], acc[m][n], 0, 0, 0);
        }
    };

    const int ntiles = K >> 6;   // always even, >= 2 here
    stage(0, 1, 0);
    asm volatile("s_waitcnt vmcnt(0)" ::: "memory");
    __builtin_amdgcn_s_barrier();
    int t = 0;
    for (; t + 2 < ntiles; t += 2) {
        stage(2, 3, (t + 1) << 6);
        asm volatile("s_waitcnt vmcnt(8)" ::: "memory");
        __builtin_amdgcn_s_barrier();
        compute(0u, 16384u);
        __builtin_amdgcn_s_barrier();
        stage(0, 1, (t + 2) << 6);
        asm volatile("s_waitcnt vmcnt(8)" ::: "memory");
        __builtin_amdgcn_s_barrier();
        compute(32768u, 49152u);
        __builtin_amdgcn_s_barrier();
    }
    // tail: tiles t (in buf0) and t+1
    stage(2, 3, (ntiles - 1) << 6);
    asm volatile("s_waitcnt vmcnt(8)" ::: "memory");
    __builtin_amdgcn_s_barrier();
    compute(0u, 16384u);
    __builtin_amdgcn_s_barrier();
    asm volatile("s_waitcnt vmcnt(0)" ::: "memory");
    __builtin_amdgcn_s_barrier();
    compute(32768u, 49152u);
    __syncthreads();

    if (OMODE == 0) {
        // bf16 repack through LDS (reuse sLDS[0..1]: 128x128 ushorts = 32KB)
        unsigned short* sOut = &sLDS[0][0];
#pragma unroll
        for (int n = 0; n < 4; ++n) {
            const int col = (wc << 6) + (n << 4) + ln15;
            const float bv = bias[bn + col];
#pragma unroll
            for (int m = 0; m < 4; ++m) {
                const int row0 = (wr << 6) + (m << 4) + (lhi << 2);
#pragma unroll
                for (int r = 0; r < 4; ++r) {
                    float x = acc[m][n][r] + bv;
                    if (GELU) x = 0.5f * x * (1.f + erff(x * 0.70710678118654752f));
                    const __hip_bfloat16 hb = __float2bfloat16(x);
                    sOut[(row0 + r) * 128 + col] = *(const unsigned short*)&hb;
                }
            }
        }
        __syncthreads();
#pragma unroll
        for (int i = 0; i < 8; ++i) {
            const int chunk = (i << 8) + tid;
            const int row = chunk >> 4, c8 = (chunk & 15) << 3;
            *(uint4*)((unsigned short*)outB + (size_t)(bm + row) * N + bn + c8) =
                *(const uint4*)(sOut + row * 128 + c8);
        }
    } else {
#pragma unroll
        for (int n = 0; n < 4; ++n) {
            const int gcn = bn + (wc << 6) + (n << 4) + ln15;
            const float bv = bias[gcn];
#pragma unroll
            for (int m = 0; m < 4; ++m) {
                const int gr0 = bm + (wr << 6) + (m << 4) + (lhi << 2);
                f32x4 v = acc[m][n];
#pragma unroll
                for (int r = 0; r < 4; ++r) {
                    const size_t o = (size_t)(gr0 + r) * N + gcn;
                    float x = v[r] + bv;
                    if (OMODE == 1) x += res[o];
                    outF[o] = x;
                }
            }
        }
    }
}

// ---------------- head: out[m][n] = A[m] . W[:,n] + bias (fp32 exact) ----------------
__global__ __launch_bounds__(256) void head_kernel(const float* __restrict__ A,
                                                   const float* __restrict__ W,
                                                   const float* __restrict__ bias,
                                                   float* __restrict__ out)
{
    const int n = blockIdx.x * 256 + threadIdx.x;
    const int m = blockIdx.y;
    if (n >= NCLS_) return;
    const float* a = A + (size_t)m * C_;
    float s = 0.f;
#pragma unroll 8
    for (int k = 0; k < C_; ++k) s = fmaf(a[k], W[(size_t)k * NCLS_ + n], s);
    out[(size_t)m * NCLS_ + n] = s + bias[n];
}

// ---------------- MFMA attention (QKV fused input, row stride 3C) ----------------
template<int NT16>
__global__ __launch_bounds__(256) void attn_mfma_kernel(const __hip_bfloat16* __restrict__ qkv,
                                                        __hip_bfloat16* __restrict__ o,
                                                        float* __restrict__ attn0,
                                                        int Nt)
{
    constexpr int NPAD = NT16 * 16;
    constexpr int PSW = (((NPAD / 8) & 7) == 0) ? 7 : 3;   // P chunk XOR key (ln15)
    constexpr int VSW = 7;                                  // V chunk XOR key (d>>3)
    constexpr int PROWB = NPAD * 2 + 16;                    // P row bytes (padded)
    constexpr int VROWB = (NPAD == 224) ? 528 : 272;        // V^T row bytes
    __shared__ unsigned short sK[NPAD * 64 + 512];          // K [key][64] linear; P after S
    __shared__ unsigned short sV[32 * VROWB];               // V^T [d][key]

    const int bh = blockIdx.x;
    const int b = bh / NH_, h = bh % NH_;
    const int qtile = blockIdx.y;
    const int tid = threadIdx.x, ln = tid & 63, wv = tid >> 6;
    const int ln15 = ln & 15, lhi = ln >> 4;
    const __hip_bfloat16* qkbase = qkv + (size_t)b * Nt * RS_;

    // ---- stage K: linear LDS dest + pre-swizzled global source ----
#pragma unroll
    for (int it = 0; it < NPAD * 8 / 256; ++it) {
        const int p = it * 256 + tid;
        int key = p >> 3;
        const int c = (p & 7) ^ (key & 7);
        if (key >= Nt) key = Nt - 1;               // clamp (masked later)
        unsigned short* dst = sK + (size_t)(it * 256 + (wv << 6)) * 8;   // wave-uniform
        gload16(dst, qkbase + (size_t)key * RS_ + C_ + (h << 6) + (c << 3));
    }
    // ---- stage V^T: 16B vector loads, scatter to padded/swizzled rows ----
#pragma unroll
    for (int it = 0; it < NPAD * 8 / 256; ++it) {
        const int e = it * 256 + tid;
        const int key = e >> 3, dc = e & 7;        // 8 d-elems per chunk
        union { uint4 u; unsigned short us[8]; } val;
        val.u = make_uint4(0u, 0u, 0u, 0u);
        if (key < Nt)
            val.u = *(const uint4*)(qkbase + (size_t)key * RS_ + 2 * C_ + (h << 6) + (dc << 3));
        const int kc = key >> 3, kb = (key & 7) << 1;
#pragma unroll
        for (int j = 0; j < 8; ++j) {
            const int d = (dc << 3) + j;
            *(unsigned short*)((char*)sV + d * VROWB + ((kc ^ ((d >> 3) & VSW)) << 4) + kb) = val.us[j];
        }
    }
    // ---- Q fragments from global ----
    const int qbase = qtile * 64 + (wv << 4);
    int qrow = qbase + ln15; if (qrow >= Nt) qrow = Nt - 1;
    const __hip_bfloat16* qp = qkbase + (size_t)qrow * RS_ + (h << 6) + (lhi << 3);
    const bf16x8 qf0 = *(const bf16x8*)qp;
    const bf16x8 qf1 = *(const bf16x8*)(qp + 32);
    __syncthreads();

    // ---- S^T = K @ Q^T ----
    f32x4 sc[NT16];
#pragma unroll
    for (int t = 0; t < NT16; ++t) {
        const int key = (t << 4) + ln15;
        const unsigned short* kr = sK + (size_t)key * 64;
        const bf16x8 k0 = *(const bf16x8*)(kr + ((lhi ^ (key & 7)) << 3));
        const bf16x8 k1 = *(const bf16x8*)(kr + (((4 + lhi) ^ (key & 7)) << 3));
        f32x4 a = {0.f, 0.f, 0.f, 0.f};
        a = __builtin_amdgcn_mfma_f32_16x16x32_bf16(k0, qf0, a, 0, 0, 0);
        a = __builtin_amdgcn_mfma_f32_16x16x32_bf16(k1, qf1, a, 0, 0, 0);
        sc[t] = a;
    }
    __syncthreads();   // all waves done reading K before P overwrites it

    // ---- softmax over keys (mask >= Nt) ----
    float mx = -1e30f;
#pragma unroll
    for (int t = 0; t < NT16; ++t)
#pragma unroll
        for (int r = 0; r < 4; ++r) {
            const int key = (t << 4) + (lhi << 2) + r;
            const float v = (key < Nt) ? sc[t][r] * 0.125f : -1e30f;
            sc[t][r] = v;
            mx = fmaxf(mx, v);
        }
    mx = fmaxf(mx, __shfl_xor(mx, 16));
    mx = fmaxf(mx, __shfl_xor(mx, 32));
    float sum = 0.f;
#pragma unroll
    for (int t = 0; t < NT16; ++t)
#pragma unroll
        for (int r = 0; r < 4; ++r) {
            const float e = expf(sc[t][r] - mx);
            sc[t][r] = e; sum += e;
        }
    sum += __shfl_xor(sum, 16);
    sum += __shfl_xor(sum, 32);
    const float inv = 1.f / sum;

    // ---- write P (bf16) into per-wave region of sK ----
    char* Pw = (char*)sK + wv * (16 * PROWB);
    const bool isQ0 = (qtile == 0) && (wv == 0) && (ln15 == 0);
#pragma unroll
    for (int t = 0; t < NT16; ++t) {
        union { unsigned short us[4]; uint2 u2; } pk;
#pragma unroll
        for (int r = 0; r < 4; ++r) {
            const float p = sc[t][r] * inv;
            const __hip_bfloat16 hb = __float2bfloat16(p);
            pk.us[r] = *(const unsigned short*)&hb;
            if (isQ0) {
                const int key = (t << 4) + (lhi << 2) + r;
                if (key < Nt) attn0[(size_t)bh * NTOK + key] = p;
            }
        }
        const int chunk = ((t << 1) + (lhi >> 1)) ^ (ln15 & PSW);
        *(uint2*)(Pw + ln15 * PROWB + (chunk << 4) + ((lhi & 1) << 3)) = pk.u2;
    }
    __syncthreads();

    // ---- O = P @ V ----
    f32x4 oa[4] = {};
#pragma unroll
    for (int s = 0; s < NPAD / 32; ++s) {
        const bf16x8 pf = *(const bf16x8*)(Pw + ln15 * PROWB +
                                           ((((s << 2) + lhi) ^ (ln15 & PSW)) << 4));
#pragma unroll
        for (int n = 0; n < 4; ++n) {
            const int d = (n << 4) + ln15;
            const bf16x8 vf = *(const bf16x8*)((char*)sV + d * VROWB +
                                               ((((s << 2) + lhi) ^ ((d >> 3) & VSW)) << 4));
            oa[n] = __builtin_amdgcn_mfma_f32_16x16x32_bf16(pf, vf, oa[n], 0, 0, 0);
        }
    }
#pragma unroll
    for (int n = 0; n < 4; ++n)
#pragma unroll
        for (int r = 0; r < 4; ++r) {
            const int qq = qbase + (lhi << 2) + r;
            if (qq < Nt)
                o[((size_t)b * Nt + qq) * C_ + (h << 6) + (n << 4) + ln15] =
                    __float2bfloat16(oa[n][r]);
        }
}

// ---------------- row + cls EMA (full layers) ----------------
__global__ __launch_bounds__(256) void row_cls_ema_kernel(const float* __restrict__ attn0,
                                                          float* __restrict__ cls, int first)
{
    const int b = blockIdx.x, t = threadIdx.x;
    if (t < NP_) {
        float s = 0.f;
#pragma unroll
        for (int h = 0; h < NH_; ++h) s += attn0[((size_t)(b * NH_ + h)) * NTOK + 1 + t];
        const int i = b * NP_ + t;
        cls[i] = first ? s : 0.5f * cls[i] + 0.5f * s;
    }
}

// ---------------- row + cls update (pruned layers) ----------------
__global__ __launch_bounds__(256) void row_cls_prune_kernel(const float* __restrict__ attn0,
                                                            const float* __restrict__ sorted,
                                                            float* __restrict__ cls)
{
    const int b = blockIdx.x, t = threadIdx.x;
    if (t < NP_) {
        float sv = sorted[b * NP_ + t];
        if (t < NKEEP) {
            float s = 0.f;
#pragma unroll
            for (int h = 0; h < NH_; ++h) s += attn0[((size_t)(b * NH_ + h)) * NTOK + 1 + t];
            sv = 0.5f * sv + 0.5f * s;
        }
        cls[b * NP_ + t] = sv;
    }
}

// ---------------- stable descending rank-sort ----------------
__global__ __launch_bounds__(256) void rank_kernel(const float* __restrict__ cls,
                                                   int* __restrict__ idx,
                                                   float* __restrict__ sorted,
                                                   float* __restrict__ ssum)
{
    __shared__ float sv[NP_];
    const int b = blockIdx.x, t = threadIdx.x;
    if (t < NP_) sv[t] = cls[b * NP_ + t];
    __syncthreads();
    float val = 0.f; int r = NP_;
    if (t < NP_) {
        val = sv[t];
        r = 0;
        for (int j = 0; j < NP_; ++j) {
            const float vj = sv[j];
            r += (vj > val || (vj == val && j < t)) ? 1 : 0;
        }
        idx[b * NP_ + r] = t;
        sorted[b * NP_ + r] = val;
    }
    const float contrib = (t < NP_ && r >= NKEEP) ? val : 0.f;
    const float tot = blockReduceSum256(contrib);
    if (t == 0) ssum[b] = tot;
}

// ---------------- build xs / fast / rep ----------------
__global__ __launch_bounds__(256) void build_xs_kernel(const float* __restrict__ x,
                                                       const int* __restrict__ idx,
                                                       const float* __restrict__ sorted,
                                                       const float* __restrict__ ssum,
                                                       float* __restrict__ xs,
                                                       float* __restrict__ fast,
                                                       float* __restrict__ rep)
{
    const int b = blockIdx.x, t = blockIdx.y, tid = threadIdx.x;
    const float* xb = x + (size_t)b * NTOK * C_;
    if (t == 0) {
#pragma unroll
        for (int j = 0; j < 3; ++j) {
            const int c = tid + j * 256;
            xs[(size_t)b * 100 * C_ + c] = xb[c];
        }
    } else if (t <= NKEEP) {
        const int src = 1 + idx[b * NP_ + (t - 1)];
#pragma unroll
        for (int j = 0; j < 3; ++j) {
            const int c = tid + j * 256;
            xs[((size_t)b * 100 + t) * C_ + c] = xb[(size_t)src * C_ + c];
        }
    } else if (t == NKEEP + 1) {
        const float inv = 1.f / ssum[b];
        float acc0 = 0.f, acc1 = 0.f, acc2 = 0.f;
        for (int jj = 0; jj < NP_ - NKEEP; ++jj) {
            const int src = 1 + idx[b * NP_ + NKEEP + jj];
            const float wgt = sorted[b * NP_ + NKEEP + jj];
            const float* xr = xb + (size_t)src * C_;
            acc0 = fmaf(xr[tid], wgt, acc0);
            acc1 = fmaf(xr[tid + 256], wgt, acc1);
            acc2 = fmaf(xr[tid + 512], wgt, acc2);
        }
        float* xsr = xs + ((size_t)b * 100 + 99) * C_;
        float* rr = rep + (size_t)b * C_;
        xsr[tid] = acc0 * inv;       rr[tid] = acc0 * inv;
        xsr[tid + 256] = acc1 * inv; rr[tid + 256] = acc1 * inv;
        xsr[tid + 512] = acc2 * inv; rr[tid + 512] = acc2 * inv;
    } else {
        const int jf = t - (NKEEP + 2);
        const int src = 1 + idx[b * NP_ + NKEEP + jf];
#pragma unroll
        for (int j = 0; j < 3; ++j) {
            const int c = tid + j * 256;
            fast[((size_t)b * (NP_ - NKEEP) + jf) * C_ + c] = xb[(size_t)src * C_ + c];
        }
    }
}

__global__ __launch_bounds__(256) void scatter_back_kernel(const float* __restrict__ xs,
                                                           const float* __restrict__ fast,
                                                           const float* __restrict__ rep,
                                                           float* __restrict__ x)
{
    const int b = blockIdx.x, t = blockIdx.y, tid = threadIdx.x;
#pragma unroll
    for (int j = 0; j < 3; ++j) {
        const int c = tid + j * 256;
        float v;
        if (t <= NKEEP)
            v = xs[((size_t)b * 100 + t) * C_ + c];
        else
            v = fast[((size_t)b * (NP_ - NKEEP) + (t - NKEEP - 1)) * C_ + c]
                + 0.5f * (xs[((size_t)b * 100 + 99) * C_ + c] - rep[(size_t)b * C_ + c]);
        x[((size_t)b * NTOK + t) * C_ + c] = v;
    }
}

// ---------------- host ----------------
extern "C" void kernel_launch(void* const* d_in, const int* in_sizes, int n_in,
                              void* d_out, int out_size, void* d_ws, size_t ws_size,
                              hipStream_t stream)
{
    (void)in_sizes; (void)n_in; (void)out_size;
    const float* x_img   = (const float*)d_in[0];
    const float* cls_tok = (const float*)d_in[1];
    const float* pos     = (const float*)d_in[2];
    const float* patch_w = (const float*)d_in[3];
    const float* patch_b = (const float*)d_in[4];
    const float* ln1_g   = (const float*)d_in[5];
    const float* ln1_b   = (const float*)d_in[6];
    const float* qk_w    = (const float*)d_in[7];
    const float* qk_b    = (const float*)d_in[8];
    const float* v_w     = (const float*)d_in[9];
    const float* v_b     = (const float*)d_in[10];
    const float* proj_w  = (const float*)d_in[11];
    const float* proj_b  = (const float*)d_in[12];
    const float* ln2_g   = (const float*)d_in[13];
    const float* ln2_b   = (const float*)d_in[14];
    const float* fc1_w   = (const float*)d_in[15];
    const float* fc1_b   = (const float*)d_in[16];
    const float* fc2_w   = (const float*)d_in[17];
    const float* fc2_b   = (const float*)d_in[18];
    const float* norm_g  = (const float*)d_in[19];
    const float* norm_b  = (const float*)d_in[20];
    const float* head_w  = (const float*)d_in[21];
    const float* head_b  = (const float*)d_in[22];

    char* base = (char*)d_ws;
    size_t off = 0;
    auto alloc = [&](size_t bytes) -> void* {
        void* p = base + off; off = (off + bytes + 255) & ~(size_t)255; return p;
    };
    float* X    = (float*)alloc((size_t)MPAD * C_ * 4);
    __hip_bfloat16* Tb   = (__hip_bfloat16*)alloc((size_t)MPAD * C_ * 2);
    __hip_bfloat16* QKVb = (__hip_bfloat16*)alloc((size_t)MPAD * RS_ * 2);
    __hip_bfloat16* Hb   = (__hip_bfloat16*)alloc((size_t)MPAD * 4 * C_ * 2);
    float* XS   = (float*)alloc((size_t)3200 * C_ * 4);
    float* FAST = (float*)alloc((size_t)B_ * (NP_ - NKEEP) * C_ * 4);
    float* REP  = (float*)alloc((size_t)B_ * C_ * 4);
    float* ATTN0= (float*)alloc((size_t)B_ * NH_ * NTOK * 4);
    float* CLS  = (float*)alloc((size_t)B_ * NP_ * 4);
    float* SORT = (float*)alloc((size_t)B_ * NP_ * 4);
    float* SSUM = (float*)alloc((size_t)B_ * 4);
    float* T0   = (float*)alloc((size_t)B_ * C_ * 4);
    int*   IDX  = (int*)alloc((size_t)B_ * NP_ * 4);
    float* BIASQKV = (float*)alloc((size_t)12 * RS_ * 4);
    __hip_bfloat16* WTpatch = (__hip_bfloat16*)alloc((size_t)C_ * C_ * 2);
    __hip_bfloat16* WTqkv   = (__hip_bfloat16*)alloc((size_t)12 * RS_ * C_ * 2);
    __hip_bfloat16* WTproj  = (__hip_bfloat16*)alloc((size_t)12 * C_ * C_ * 2);
    __hip_bfloat16* WTfc1   = (__hip_bfloat16*)alloc((size_t)12 * C_ * 4 * C_ * 2);
    __hip_bfloat16* WTfc2   = (__hip_bfloat16*)alloc((size_t)12 * 4 * C_ * C_ * 2);
    if (off > ws_size) return;

    __hip_bfloat16* Ob    = Hb;          // attn output aliases Hb
    __hip_bfloat16* PATCH = Hb;
    float*          PEMB  = (float*)QKVb;

    const dim3 blk(256);

    // ---- weight transposes (fp32 [K][N] -> bf16 [N][K]) ----
    transpose_bf16_kernel<<<dim3(24, 24, 1), blk, 0, stream>>>(patch_w, WTpatch, C_, C_, (long long)C_ * C_, 0);
    transpose_bf16_kernel<<<dim3(48, 24, 12), blk, 0, stream>>>(qk_w, WTqkv, C_, 2 * C_, (long long)RS_ * C_, 0);
    transpose_bf16_kernel<<<dim3(24, 24, 12), blk, 0, stream>>>(v_w, WTqkv, C_, C_, (long long)RS_ * C_, (long long)2 * C_ * C_);
    transpose_bf16_kernel<<<dim3(24, 24, 12), blk, 0, stream>>>(proj_w, WTproj, C_, C_, (long long)C_ * C_, 0);
    transpose_bf16_kernel<<<dim3(96, 24, 12), blk, 0, stream>>>(fc1_w, WTfc1, C_, 4 * C_, (long long)4 * C_ * C_, 0);
    transpose_bf16_kernel<<<dim3(24, 96, 12), blk, 0, stream>>>(fc2_w, WTfc2, 4 * C_, C_, (long long)4 * C_ * C_, 0);
    concat_bias_kernel<<<(12 * RS_ + 255) / 256, blk, 0, stream>>>(qk_b, v_b, BIASQKV);

    auto runBlock = [&](int i, float* xb, int Nt) {
        const int M = B_ * Nt;
        const int mt = (M + 127) >> 7;
        const int qtiles = (Nt + 63) >> 6;
        ln_kernel<<<(M + 3) / 4, blk, 0, stream>>>(xb, ln1_g + i * C_, ln1_b + i * C_, Tb, nullptr, C_, M);
        gemm_bf16_kernel<0, 0><<<dim3(RS_ / 128, mt), blk, 0, stream>>>(
            Tb, WTqkv + (size_t)i * RS_ * C_, BIASQKV + (size_t)i * RS_, nullptr, nullptr, QKVb, C_, RS_);
        if (Nt == NTOK)
            attn_mfma_kernel<14><<<dim3(B_ * NH_, qtiles), blk, 0, stream>>>(QKVb, Ob, ATTN0, Nt);
        else
            attn_mfma_kernel<8><<<dim3(B_ * NH_, qtiles), blk, 0, stream>>>(QKVb, Ob, ATTN0, Nt);
        gemm_bf16_kernel<0, 1><<<dim3(6, mt), blk, 0, stream>>>(
            Ob, WTproj + (size_t)i * C_ * C_, proj_b + (size_t)i * C_, xb, xb, nullptr, C_, C_);
        ln_kernel<<<(M + 3) / 4, blk, 0, stream>>>(xb, ln2_g + i * C_, ln2_b + i * C_, Tb, nullptr, C_, M);
        gemm_bf16_kernel<1, 0><<<dim3(24, mt), blk, 0, stream>>>(
            Tb, WTfc1 + (size_t)i * C_ * 4 * C_, fc1_b + (size_t)i * 4 * C_, nullptr, nullptr, Hb, C_, 4 * C_);
        gemm_bf16_kernel<0, 1><<<dim3(6, mt), blk, 0, stream>>>(
            Hb, WTfc2 + (size_t)i * 4 * C_ * C_, fc2_b + (size_t)i * C_, xb, xb, nullptr, 4 * C_, C_);
    };

    // ---- patch embedding ----
    patchify_kernel<<<B_ * NP_, blk, 0, stream>>>(x_img, PATCH);
    gemm_bf16_kernel<0, 2><<<dim3(6, 49), blk, 0, stream>>>(
        PATCH, WTpatch, patch_b, nullptr, PEMB, nullptr, C_, C_);
    assemble_x_kernel<<<dim3(B_, NTOK), blk, 0, stream>>>(PEMB, cls_tok, pos, X);

    // ---- 12 transformer blocks ----
    for (int i = 0; i < 12; ++i) {
        if (i < 4) {
            runBlock(i, X, NTOK);
            row_cls_ema_kernel<<<B_, blk, 0, stream>>>(ATTN0, CLS, i == 0 ? 1 : 0);
        } else {
            rank_kernel<<<B_, blk, 0, stream>>>(CLS, IDX, SORT, SSUM);
            build_xs_kernel<<<dim3(B_, 198), blk, 0, stream>>>(X, IDX, SORT, SSUM, XS, FAST, REP);
            runBlock(i, XS, 100);
            scatter_back_kernel<<<dim3(B_, NTOK), blk, 0, stream>>>(XS, FAST, REP, X);
            row_cls_prune_kernel<<<B_, blk, 0, stream>>>(ATTN0, SORT, CLS);
        }
    }

    // ---- final LN (token 0 only) + head (fp32 exact) ----
    ln_kernel<<<8, blk, 0, stream>>>(X, norm_g, norm_b, nullptr, T0, (long long)NTOK * C_, B_);
    head_kernel<<<dim3(4, B_), blk, 0, stream>>>(T0, head_w, head_b, (float*)d_out);
}